// Round 1
// baseline (2397.934 us; speedup 1.0000x reference)
//
#include <hip/hip_runtime.h>
#include <math.h>

#define BB 64
#define NN 1224
#define CC 1024
#define DD 256
#define PP 200
#define TT 1024
#define HH 4
#define HDD 64

// ---------------- workspace layout (floats) ----------------
// down  : [BB*NN*DD]                     gelu(x @ down_W^T + b)
// q,k,v : each [BB*HH*PP*HDD]            head-major for attention
// sa    : [BB*PP*DD]                     attention output
// sa2   : [BB*PP*DD]                     after out_proj
// pout  : [BB*PP*DD]                     cross-attention output
// scores: aliases [q..sa] (exactly BB*PP*TT floats) -- q/k/v/sa dead by then
static const size_t DOWNSZ = (size_t)BB * NN * DD;   // 20,054,016
static const size_t QSZ    = (size_t)BB * HH * PP * HDD; // 3,276,800
static const size_t OFF_DOWN = 0;
static const size_t OFF_Q    = OFF_DOWN + DOWNSZ;
static const size_t OFF_K    = OFF_Q + QSZ;
static const size_t OFF_V    = OFF_K + QSZ;
static const size_t OFF_SA   = OFF_V + QSZ;
static const size_t OFF_SA2  = OFF_SA + QSZ;
static const size_t OFF_POUT = OFF_SA2 + QSZ;
static const size_t OFF_SCORES = OFF_Q;              // BB*PP*TT = 13,107,200

// ---------------- shared GEMM pieces ----------------
#define GEMM_PROLOGUE \
  const int tid = threadIdx.x; \
  const int tx = tid & 15, ty = tid >> 4; \
  __shared__ __align__(16) float As[16][68]; \
  __shared__ __align__(16) float Bs[16][68]; \
  float acc[4][4] = {{0.f}};

#define GEMM_STEP \
  __syncthreads(); \
  _Pragma("unroll") \
  for (int k = 0; k < 16; ++k) { \
    const float4 a4 = *(const float4*)&As[k][ty * 4]; \
    const float4 b4 = *(const float4*)&Bs[k][tx * 4]; \
    acc[0][0] += a4.x * b4.x; acc[0][1] += a4.x * b4.y; acc[0][2] += a4.x * b4.z; acc[0][3] += a4.x * b4.w; \
    acc[1][0] += a4.y * b4.x; acc[1][1] += a4.y * b4.y; acc[1][2] += a4.y * b4.z; acc[1][3] += a4.y * b4.w; \
    acc[2][0] += a4.z * b4.x; acc[2][1] += a4.z * b4.y; acc[2][2] += a4.z * b4.z; acc[2][3] += a4.z * b4.w; \
    acc[3][0] += a4.w * b4.x; acc[3][1] += a4.w * b4.y; acc[3][2] += a4.w * b4.z; acc[3][3] += a4.w * b4.w; \
  } \
  __syncthreads();

// ---------------- K1: down = gelu(x @ down_W^T + b) ----------------
// M = BB*NN = 78336 (exact 1224 tiles), N = 256, K = 1024
__global__ __launch_bounds__(256) void k_down(const float* __restrict__ x,
                                              const float* __restrict__ W,
                                              const float* __restrict__ bias,
                                              float* __restrict__ out)
{
  GEMM_PROLOGUE
  const int m0 = blockIdx.y * 64, n0 = blockIdx.x * 64;
  for (int k0 = 0; k0 < CC; k0 += 16) {
#pragma unroll
    for (int i = 0; i < 4; ++i) {
      const int l = tid + i * 256;
      const int kl = l & 15, ml = l >> 4;
      As[kl][ml] = x[(size_t)(m0 + ml) * CC + k0 + kl];
      Bs[kl][ml] = W[(size_t)(n0 + ml) * CC + k0 + kl];
    }
    GEMM_STEP
  }
#pragma unroll
  for (int i = 0; i < 4; ++i) {
    const int m = m0 + ty * 4 + i;
#pragma unroll
    for (int j = 0; j < 4; ++j) {
      const int n = n0 + tx * 4 + j;
      float v = acc[i][j] + bias[n];
      v = 0.5f * v * (1.f + erff(v * 0.7071067811865475f));
      out[(size_t)m * DD + n] = v;
    }
  }
}

// ---------------- K2: qkv = prompt @ in_proj_W^T + b, scattered to (B,H,P,hd) ----------------
// M = BB*PP = 12800 (exact 200 tiles), N = 768, K = 256
__global__ __launch_bounds__(256) void k_qkv(const float* __restrict__ down,
                                             const float* __restrict__ W,
                                             const float* __restrict__ bias,
                                             float* __restrict__ qb,
                                             float* __restrict__ kb,
                                             float* __restrict__ vb)
{
  GEMM_PROLOGUE
  const int m0 = blockIdx.y * 64, n0 = blockIdx.x * 64;
  for (int k0 = 0; k0 < DD; k0 += 16) {
#pragma unroll
    for (int i = 0; i < 4; ++i) {
      const int l = tid + i * 256;
      const int kl = l & 15, ml = l >> 4;
      const int m = m0 + ml;
      const int b = m / PP, p = m % PP;
      As[kl][ml] = down[((size_t)b * NN + p) * DD + k0 + kl];
      Bs[kl][ml] = W[(size_t)(n0 + ml) * DD + k0 + kl];
    }
    GEMM_STEP
  }
#pragma unroll
  for (int i = 0; i < 4; ++i) {
    const int m = m0 + ty * 4 + i;
    const int b = m / PP, p = m % PP;
#pragma unroll
    for (int j = 0; j < 4; ++j) {
      const int n = n0 + tx * 4 + j;
      const float v = acc[i][j] + bias[n];
      const int which = n >> 8, d = n & 255, h = d >> 6, dd = d & 63;
      float* dst = (which == 0) ? qb : ((which == 1) ? kb : vb);
      dst[(((size_t)(b * HH + h)) * PP + p) * HDD + dd] = v;
    }
  }
}

// ---------------- K3: self-attention, one wave per (b,h,p) ----------------
__global__ __launch_bounds__(64) void k_attn(const float* __restrict__ qb,
                                             const float* __restrict__ kb,
                                             const float* __restrict__ vb,
                                             float* __restrict__ sa)
{
  const int bid = blockIdx.x;           // (b*HH + h)*PP + p
  const int p = bid % PP;
  const int bh = bid / PP;
  const int lane = threadIdx.x;
  const float* qrow = qb + ((size_t)bh * PP + p) * HDD;
  const float* Km = kb + (size_t)bh * PP * HDD;
  const float* Vm = vb + (size_t)bh * PP * HDD;
  const float qd = qrow[lane];
  __shared__ float s[PP];
  for (int j = 0; j < PP; ++j) {
    float prod = qd * Km[(size_t)j * HDD + lane];
#pragma unroll
    for (int off = 32; off; off >>= 1) prod += __shfl_xor(prod, off);
    if (lane == 0) s[j] = prod * 0.125f;  // 1/sqrt(64)
  }
  __syncthreads();
  float mx = -1e30f;
  for (int j = lane; j < PP; j += 64) mx = fmaxf(mx, s[j]);
#pragma unroll
  for (int off = 32; off; off >>= 1) mx = fmaxf(mx, __shfl_xor(mx, off));
  float sum = 0.f;
  for (int j = lane; j < PP; j += 64) { const float e = expf(s[j] - mx); s[j] = e; sum += e; }
#pragma unroll
  for (int off = 32; off; off >>= 1) sum += __shfl_xor(sum, off);
  __syncthreads();
  const float inv = 1.f / sum;
  float accv = 0.f;
  for (int j = 0; j < PP; ++j) accv += s[j] * Vm[(size_t)j * HDD + lane];
  const int b = bh >> 2, h = bh & 3;
  sa[((size_t)(b * PP + p)) * DD + h * HDD + lane] = accv * inv;
}

// ---------------- K4: sa2 = sa @ out_proj_W^T + b ----------------
// M = 12800, N = 256, K = 256
__global__ __launch_bounds__(256) void k_oproj(const float* __restrict__ A,
                                               const float* __restrict__ W,
                                               const float* __restrict__ bias,
                                               float* __restrict__ out)
{
  GEMM_PROLOGUE
  const int m0 = blockIdx.y * 64, n0 = blockIdx.x * 64;
  for (int k0 = 0; k0 < DD; k0 += 16) {
#pragma unroll
    for (int i = 0; i < 4; ++i) {
      const int l = tid + i * 256;
      const int kl = l & 15, ml = l >> 4;
      As[kl][ml] = A[(size_t)(m0 + ml) * DD + k0 + kl];
      Bs[kl][ml] = W[(size_t)(n0 + ml) * DD + k0 + kl];
    }
    GEMM_STEP
  }
#pragma unroll
  for (int i = 0; i < 4; ++i) {
    const int m = m0 + ty * 4 + i;
#pragma unroll
    for (int j = 0; j < 4; ++j) {
      const int n = n0 + tx * 4 + j;
      out[(size_t)m * DD + n] = acc[i][j] + bias[n];
    }
  }
}

// ---------------- K5: scores[b,p,t] = (sa2[b,p,:] . tok[b,t,:]) / 16 ----------------
// grid (TT/64, 4, BB); K = 256
__global__ __launch_bounds__(256) void k_scores(const float* __restrict__ sa2,
                                                const float* __restrict__ down,
                                                float* __restrict__ scores)
{
  GEMM_PROLOGUE
  const int b = blockIdx.z;
  const int p0 = blockIdx.y * 64, t0 = blockIdx.x * 64;
  for (int k0 = 0; k0 < DD; k0 += 16) {
#pragma unroll
    for (int i = 0; i < 4; ++i) {
      const int l = tid + i * 256;
      const int kl = l & 15, ml = l >> 4;
      const int p = p0 + ml;
      As[kl][ml] = (p < PP) ? sa2[((size_t)b * PP + p) * DD + k0 + kl] : 0.f;
      Bs[kl][ml] = down[((size_t)b * NN + PP + t0 + ml) * DD + k0 + kl];
    }
    GEMM_STEP
  }
#pragma unroll
  for (int i = 0; i < 4; ++i) {
    const int p = p0 + ty * 4 + i;
    if (p < PP) {
#pragma unroll
      for (int j = 0; j < 4; ++j) {
        const int t = t0 + tx * 4 + j;
        scores[((size_t)b * PP + p) * TT + t] = acc[i][j] * 0.0625f; // 256^-0.5
      }
    }
  }
}

// ---------------- K5b: row softmax over 1024 ----------------
__global__ __launch_bounds__(256) void k_softmax(float* __restrict__ s)
{
  const int row = blockIdx.x;
  float* r = s + (size_t)row * TT;
  const int t = threadIdx.x;
  const int lane = t & 63, w = t >> 6;
  __shared__ float red[4];
  float v[4];
  float mx = -1e30f;
#pragma unroll
  for (int i = 0; i < 4; ++i) { v[i] = r[t + i * 256]; mx = fmaxf(mx, v[i]); }
#pragma unroll
  for (int off = 32; off; off >>= 1) mx = fmaxf(mx, __shfl_xor(mx, off));
  if (lane == 0) red[w] = mx;
  __syncthreads();
  mx = fmaxf(fmaxf(red[0], red[1]), fmaxf(red[2], red[3]));
  __syncthreads();
  float sum = 0.f;
#pragma unroll
  for (int i = 0; i < 4; ++i) { v[i] = expf(v[i] - mx); sum += v[i]; }
#pragma unroll
  for (int off = 32; off; off >>= 1) sum += __shfl_xor(sum, off);
  if (lane == 0) red[w] = sum;
  __syncthreads();
  sum = red[0] + red[1] + red[2] + red[3];
  const float inv = 1.f / sum;
#pragma unroll
  for (int i = 0; i < 4; ++i) r[t + i * 256] = v[i] * inv;
}

// ---------------- K6: pout[b,p,e] = sum_t scores[b,p,t] * tok[b,t,e]  (A@B) ----------------
// grid (DD/64, 4, BB); K = 1024
__global__ __launch_bounds__(256) void k_pout(const float* __restrict__ scores,
                                              const float* __restrict__ down,
                                              float* __restrict__ out)
{
  GEMM_PROLOGUE
  const int b = blockIdx.z;
  const int p0 = blockIdx.y * 64, n0 = blockIdx.x * 64;
  for (int k0 = 0; k0 < TT; k0 += 16) {
#pragma unroll
    for (int i = 0; i < 4; ++i) {
      const int l = tid + i * 256;
      {
        const int kl = l & 15, ml = l >> 4;
        const int p = p0 + ml;
        As[kl][ml] = (p < PP) ? scores[((size_t)b * PP + p) * TT + k0 + kl] : 0.f;
      }
      {
        const int nl = l & 63, kl2 = l >> 6;
        Bs[kl2][nl] = down[((size_t)b * NN + PP + k0 + kl2) * DD + n0 + nl];
      }
    }
    GEMM_STEP
  }
#pragma unroll
  for (int i = 0; i < 4; ++i) {
    const int p = p0 + ty * 4 + i;
    if (p < PP) {
#pragma unroll
      for (int j = 0; j < 4; ++j) {
        out[((size_t)b * PP + p) * DD + n0 + tx * 4 + j] = acc[i][j];
      }
    }
  }
}

// ---------------- K7: out = gate * (combined @ up_W^T + b) ----------------
// combined row r: r<PP -> pout, else -> down(tok). grid (CC/64, 20, BB); K=256
__global__ __launch_bounds__(256) void k_up(const float* __restrict__ pout,
                                            const float* __restrict__ down,
                                            const float* __restrict__ W,
                                            const float* __restrict__ bias,
                                            const float* __restrict__ gate,
                                            float* __restrict__ out)
{
  GEMM_PROLOGUE
  const int b = blockIdx.z;
  const int r0 = blockIdx.y * 64, n0 = blockIdx.x * 64;
  for (int k0 = 0; k0 < DD; k0 += 16) {
#pragma unroll
    for (int i = 0; i < 4; ++i) {
      const int l = tid + i * 256;
      const int kl = l & 15, ml = l >> 4;
      const int r = r0 + ml;
      float av = 0.f;
      if (r < NN) {
        av = (r < PP) ? pout[((size_t)b * PP + r) * DD + k0 + kl]
                      : down[((size_t)b * NN + r) * DD + k0 + kl];
      }
      As[kl][ml] = av;
      Bs[kl][ml] = W[(size_t)(n0 + ml) * DD + k0 + kl];
    }
    GEMM_STEP
  }
  const float g = gate[0];
#pragma unroll
  for (int i = 0; i < 4; ++i) {
    const int r = r0 + ty * 4 + i;
    if (r < NN) {
#pragma unroll
      for (int j = 0; j < 4; ++j) {
        const int n = n0 + tx * 4 + j;
        out[((size_t)b * NN + r) * CC + n] = (acc[i][j] + bias[n]) * g;
      }
    }
  }
}

extern "C" void kernel_launch(void* const* d_in, const int* in_sizes, int n_in,
                              void* d_out, int out_size, void* d_ws, size_t ws_size,
                              hipStream_t stream) {
  const float* x          = (const float*)d_in[0];
  const float* down_W     = (const float*)d_in[1];
  const float* down_b     = (const float*)d_in[2];
  const float* up_W       = (const float*)d_in[3];
  const float* up_b       = (const float*)d_in[4];
  const float* in_proj_W  = (const float*)d_in[5];
  const float* in_proj_b  = (const float*)d_in[6];
  const float* out_proj_W = (const float*)d_in[7];
  const float* out_proj_b = (const float*)d_in[8];
  const float* gate       = (const float*)d_in[9];
  float* out = (float*)d_out;

  float* ws     = (float*)d_ws;
  float* down   = ws + OFF_DOWN;
  float* qb     = ws + OFF_Q;
  float* kb     = ws + OFF_K;
  float* vb     = ws + OFF_V;
  float* sa     = ws + OFF_SA;
  float* sa2    = ws + OFF_SA2;
  float* pout   = ws + OFF_POUT;
  float* scores = ws + OFF_SCORES;   // aliases q/k/v/sa (dead by then)

  k_down<<<dim3(DD / 64, (BB * NN) / 64), 256, 0, stream>>>(x, down_W, down_b, down);
  k_qkv<<<dim3((3 * DD) / 64, (BB * PP) / 64), 256, 0, stream>>>(down, in_proj_W, in_proj_b, qb, kb, vb);
  k_attn<<<BB * HH * PP, 64, 0, stream>>>(qb, kb, vb, sa);
  k_oproj<<<dim3(DD / 64, (BB * PP) / 64), 256, 0, stream>>>(sa, out_proj_W, out_proj_b, sa2);
  k_scores<<<dim3(TT / 64, 4, BB), 256, 0, stream>>>(sa2, down, scores);
  k_softmax<<<BB * PP, 256, 0, stream>>>(scores);
  k_pout<<<dim3(DD / 64, 4, BB), 256, 0, stream>>>(scores, down, pout);
  k_up<<<dim3(CC / 64, 20, BB), 256, 0, stream>>>(pout, down, up_W, up_b, gate, out);
}

// Round 2
// 1349.924 us; speedup vs baseline: 1.7763x; 1.7763x over previous
//
#include <hip/hip_runtime.h>
#include <math.h>

#define BB 64
#define NN 1224
#define CC 1024
#define DD 256
#define PP 200
#define TT 1024
#define HH 4
#define HDD 64

typedef __attribute__((ext_vector_type(8))) short bf16x8;
typedef __attribute__((ext_vector_type(4))) float f32x4;

__device__ __forceinline__ unsigned short f2bf(float f) {
  union { float f; unsigned int u; } v; v.f = f;
  unsigned int r = v.u + 0x7FFF + ((v.u >> 16) & 1);
  return (unsigned short)(r >> 16);
}
__device__ __forceinline__ float bf2f(unsigned short h) {
  union { unsigned int u; float f; } v; v.u = ((unsigned int)h) << 16;
  return v.f;
}

// ---------------- workspace layout (floats) ----------------
static const size_t DOWNSZ = (size_t)BB * NN * DD;       // 20,054,016
static const size_t QSZ    = (size_t)BB * HH * PP * HDD; // 3,276,800
static const size_t OFF_DOWN = 0;
static const size_t OFF_Q    = OFF_DOWN + DOWNSZ;
static const size_t OFF_K    = OFF_Q + QSZ;
static const size_t OFF_V    = OFF_K + QSZ;
static const size_t OFF_SA   = OFF_V + QSZ;
static const size_t OFF_SA2  = OFF_SA + QSZ;
static const size_t OFF_POUT = OFF_SA2 + QSZ;
static const size_t OFF_SCORES = OFF_Q;                  // aliases q/k/v/sa (dead)

// ================= bf16 MFMA GEMM: down = gelu(x @ W^T + b) =================
// M=78336, N=256 (one tile), K=1024. Tile 128x256, BK=64, 8 waves.
__global__ __launch_bounds__(512) void k_down_mfma(const float* __restrict__ x,
                                                   const float* __restrict__ W,
                                                   const float* __restrict__ bias,
                                                   float* __restrict__ out)
{
  __shared__ unsigned short Abuf[128 * 64];  // XOR-swizzled
  __shared__ unsigned short Bbuf[256 * 64];
  const int tid = threadIdx.x;
  const int lane = tid & 63, wave = tid >> 6;
  const int wm = wave >> 2, wn = wave & 3;  // 2 (M) x 4 (N)
  const int m0 = blockIdx.x * 128;
  f32x4 acc[4][4] = {};

  const int rstage = tid >> 4;          // 0..31
  const int kc = (tid & 15) * 4;        // 0..60

  for (int k0 = 0; k0 < CC; k0 += 64) {
    __syncthreads();
#pragma unroll
    for (int i = 0; i < 4; ++i) {       // A: 128 rows
      const int r = rstage + 32 * i;
      const float4 v = *(const float4*)&x[(size_t)(m0 + r) * CC + k0 + kc];
      uint2 p;
      p.x = (unsigned int)f2bf(v.x) | ((unsigned int)f2bf(v.y) << 16);
      p.y = (unsigned int)f2bf(v.z) | ((unsigned int)f2bf(v.w) << 16);
      const int byte = (r * 128 + kc * 2) ^ ((r & 7) << 4);
      *(uint2*)((char*)Abuf + byte) = p;
    }
#pragma unroll
    for (int i = 0; i < 8; ++i) {       // B: 256 rows (down_W is N x K)
      const int r = rstage + 32 * i;
      const float4 v = *(const float4*)&W[(size_t)r * CC + k0 + kc];
      uint2 p;
      p.x = (unsigned int)f2bf(v.x) | ((unsigned int)f2bf(v.y) << 16);
      p.y = (unsigned int)f2bf(v.z) | ((unsigned int)f2bf(v.w) << 16);
      const int byte = (r * 128 + kc * 2) ^ ((r & 7) << 4);
      *(uint2*)((char*)Bbuf + byte) = p;
    }
    __syncthreads();
#pragma unroll
    for (int kk = 0; kk < 64; kk += 32) {
      bf16x8 af[4], bfr[4];
#pragma unroll
      for (int mi = 0; mi < 4; ++mi) {
        const int R = wm * 64 + mi * 16 + (lane & 15);
        const int byte = (R * 128 + (kk + (lane >> 4) * 8) * 2) ^ ((R & 7) << 4);
        af[mi] = *(const bf16x8*)((const char*)Abuf + byte);
      }
#pragma unroll
      for (int ni = 0; ni < 4; ++ni) {
        const int R = wn * 64 + ni * 16 + (lane & 15);
        const int byte = (R * 128 + (kk + (lane >> 4) * 8) * 2) ^ ((R & 7) << 4);
        bfr[ni] = *(const bf16x8*)((const char*)Bbuf + byte);
      }
#pragma unroll
      for (int mi = 0; mi < 4; ++mi)
#pragma unroll
        for (int ni = 0; ni < 4; ++ni)
          acc[mi][ni] = __builtin_amdgcn_mfma_f32_16x16x32_bf16(af[mi], bfr[ni], acc[mi][ni], 0, 0, 0);
    }
  }
#pragma unroll
  for (int mi = 0; mi < 4; ++mi) {
#pragma unroll
    for (int ni = 0; ni < 4; ++ni) {
      const int col = wn * 64 + ni * 16 + (lane & 15);
      const float bv = bias[col];
#pragma unroll
      for (int r = 0; r < 4; ++r) {
        const int row = m0 + wm * 64 + mi * 16 + (lane >> 4) * 4 + r;
        float v = acc[mi][ni][r] + bv;
        v = 0.5f * v * (1.f + erff(v * 0.7071067811865475f));
        out[(size_t)row * DD + col] = v;
      }
    }
  }
}

// ================= bf16 MFMA GEMM: out = gate*(combined @ up_W^T + b) =================
// M=78336 (composite rows), N=1024 (4 tiles of 256), K=256. Tile 128x256, BK=64, 8 waves.
__global__ __launch_bounds__(512) void k_up_mfma(const float* __restrict__ pout,
                                                 const float* __restrict__ down,
                                                 const float* __restrict__ W,
                                                 const float* __restrict__ bias,
                                                 const float* __restrict__ gate,
                                                 float* __restrict__ out)
{
  __shared__ unsigned short Abuf[128 * 64];
  __shared__ unsigned short Bbuf[256 * 64];
  const int tid = threadIdx.x;
  const int lane = tid & 63, wave = tid >> 6;
  const int wm = wave >> 2, wn = wave & 3;
  const int m0 = blockIdx.x * 128;
  const int n0 = blockIdx.y * 256;
  f32x4 acc[4][4] = {};

  const int rstage = tid >> 4;
  const int kc = (tid & 15) * 4;

  for (int k0 = 0; k0 < DD; k0 += 64) {
    __syncthreads();
#pragma unroll
    for (int i = 0; i < 4; ++i) {
      const int r = rstage + 32 * i;
      const int m = m0 + r;
      const int b = m / NN;
      const int rr = m - b * NN;
      const float* src = (rr < PP) ? &pout[((size_t)(b * PP + rr)) * DD]
                                   : &down[((size_t)(b * NN + rr)) * DD];
      const float4 v = *(const float4*)&src[k0 + kc];
      uint2 p;
      p.x = (unsigned int)f2bf(v.x) | ((unsigned int)f2bf(v.y) << 16);
      p.y = (unsigned int)f2bf(v.z) | ((unsigned int)f2bf(v.w) << 16);
      const int byte = (r * 128 + kc * 2) ^ ((r & 7) << 4);
      *(uint2*)((char*)Abuf + byte) = p;
    }
#pragma unroll
    for (int i = 0; i < 8; ++i) {
      const int r = rstage + 32 * i;
      const float4 v = *(const float4*)&W[(size_t)(n0 + r) * DD + k0 + kc];
      uint2 p;
      p.x = (unsigned int)f2bf(v.x) | ((unsigned int)f2bf(v.y) << 16);
      p.y = (unsigned int)f2bf(v.z) | ((unsigned int)f2bf(v.w) << 16);
      const int byte = (r * 128 + kc * 2) ^ ((r & 7) << 4);
      *(uint2*)((char*)Bbuf + byte) = p;
    }
    __syncthreads();
#pragma unroll
    for (int kk = 0; kk < 64; kk += 32) {
      bf16x8 af[4], bfr[4];
#pragma unroll
      for (int mi = 0; mi < 4; ++mi) {
        const int R = wm * 64 + mi * 16 + (lane & 15);
        const int byte = (R * 128 + (kk + (lane >> 4) * 8) * 2) ^ ((R & 7) << 4);
        af[mi] = *(const bf16x8*)((const char*)Abuf + byte);
      }
#pragma unroll
      for (int ni = 0; ni < 4; ++ni) {
        const int R = wn * 64 + ni * 16 + (lane & 15);
        const int byte = (R * 128 + (kk + (lane >> 4) * 8) * 2) ^ ((R & 7) << 4);
        bfr[ni] = *(const bf16x8*)((const char*)Bbuf + byte);
      }
#pragma unroll
      for (int mi = 0; mi < 4; ++mi)
#pragma unroll
        for (int ni = 0; ni < 4; ++ni)
          acc[mi][ni] = __builtin_amdgcn_mfma_f32_16x16x32_bf16(af[mi], bfr[ni], acc[mi][ni], 0, 0, 0);
    }
  }
  const float g = gate[0];
#pragma unroll
  for (int mi = 0; mi < 4; ++mi) {
#pragma unroll
    for (int ni = 0; ni < 4; ++ni) {
      const int col = n0 + wn * 64 + ni * 16 + (lane & 15);
      const float bv = bias[col];
#pragma unroll
      for (int r = 0; r < 4; ++r) {
        const int row = m0 + wm * 64 + mi * 16 + (lane >> 4) * 4 + r;
        out[(size_t)row * CC + col] = (acc[mi][ni][r] + bv) * g;
      }
    }
  }
}

// ---------------- fp32 tile GEMM pieces (unchanged kernels) ----------------
#define GEMM_PROLOGUE \
  const int tid = threadIdx.x; \
  const int tx = tid & 15, ty = tid >> 4; \
  __shared__ __align__(16) float As[16][68]; \
  __shared__ __align__(16) float Bs[16][68]; \
  float acc[4][4] = {{0.f}};

#define GEMM_STEP \
  __syncthreads(); \
  _Pragma("unroll") \
  for (int k = 0; k < 16; ++k) { \
    const float4 a4 = *(const float4*)&As[k][ty * 4]; \
    const float4 b4 = *(const float4*)&Bs[k][tx * 4]; \
    acc[0][0] += a4.x * b4.x; acc[0][1] += a4.x * b4.y; acc[0][2] += a4.x * b4.z; acc[0][3] += a4.x * b4.w; \
    acc[1][0] += a4.y * b4.x; acc[1][1] += a4.y * b4.y; acc[1][2] += a4.y * b4.z; acc[1][3] += a4.y * b4.w; \
    acc[2][0] += a4.z * b4.x; acc[2][1] += a4.z * b4.y; acc[2][2] += a4.z * b4.z; acc[2][3] += a4.z * b4.w; \
    acc[3][0] += a4.w * b4.x; acc[3][1] += a4.w * b4.y; acc[3][2] += a4.w * b4.z; acc[3][3] += a4.w * b4.w; \
  } \
  __syncthreads();

// K2: qkv = prompt @ in_proj_W^T + b -> scattered (B,H,P,hd)
__global__ __launch_bounds__(256) void k_qkv(const float* __restrict__ down,
                                             const float* __restrict__ W,
                                             const float* __restrict__ bias,
                                             float* __restrict__ qb,
                                             float* __restrict__ kb,
                                             float* __restrict__ vb)
{
  GEMM_PROLOGUE
  const int m0 = blockIdx.y * 64, n0 = blockIdx.x * 64;
  for (int k0 = 0; k0 < DD; k0 += 16) {
#pragma unroll
    for (int i = 0; i < 4; ++i) {
      const int l = tid + i * 256;
      const int kl = l & 15, ml = l >> 4;
      const int m = m0 + ml;
      const int b = m / PP, p = m % PP;
      As[kl][ml] = down[((size_t)b * NN + p) * DD + k0 + kl];
      Bs[kl][ml] = W[(size_t)(n0 + ml) * DD + k0 + kl];
    }
    GEMM_STEP
  }
#pragma unroll
  for (int i = 0; i < 4; ++i) {
    const int m = m0 + ty * 4 + i;
    const int b = m / PP, p = m % PP;
#pragma unroll
    for (int j = 0; j < 4; ++j) {
      const int n = n0 + tx * 4 + j;
      const float v = acc[i][j] + bias[n];
      const int which = n >> 8, d = n & 255, h = d >> 6, dd = d & 63;
      float* dst = (which == 0) ? qb : ((which == 1) ? kb : vb);
      dst[(((size_t)(b * HH + h)) * PP + p) * HDD + dd] = v;
    }
  }
}

// ================= K3: self-attention v2: one block per (b,h,half) =================
__global__ __launch_bounds__(256) void k_attn2(const float* __restrict__ qb,
                                               const float* __restrict__ kb,
                                               const float* __restrict__ vb,
                                               float* __restrict__ sa)
{
  __shared__ unsigned short Kt[HDD][PP];  // transposed, bf16
  __shared__ unsigned short Vt[PP][HDD];  // row-major, bf16
  const int bh = blockIdx.x >> 1;
  const int half = blockIdx.x & 1;
  const int tid = threadIdx.x;
  const int lane = tid & 63, wave = tid >> 6;
  const size_t base = (size_t)bh * (PP * HDD);

  // stage K (transposed) and V, fp32 -> bf16
#pragma unroll
  for (int i = 0; i < 25; ++i) {
    const int idx2 = tid + 256 * i;       // float2 index, 0..6399
    const int e = idx2 * 2;
    const int j = e >> 6, d = e & 63;     // d even
    const float2 kv = *(const float2*)(kb + base + e);
    Kt[d][j] = f2bf(kv.x);
    Kt[d + 1][j] = f2bf(kv.y);
    const float2 vv = *(const float2*)(vb + base + e);
    const unsigned int pk = (unsigned int)f2bf(vv.x) | ((unsigned int)f2bf(vv.y) << 16);
    *(unsigned int*)&Vt[j][d] = pk;
  }
  __syncthreads();

  const int b_ = bh >> 2, h = bh & 3;
  for (int r = 0; r < 25; ++r) {
    const int p = half * 100 + wave * 25 + r;
    // q row into registers (broadcast loads)
    float qv[64];
    const float4* q4 = (const float4*)(qb + base + (size_t)p * HDD);
#pragma unroll
    for (int i = 0; i < 16; ++i) {
      const float4 t = q4[i];
      qv[4 * i] = t.x; qv[4 * i + 1] = t.y; qv[4 * i + 2] = t.z; qv[4 * i + 3] = t.w;
    }
    // QK^T: lanes over j
    float sreg[4];
#pragma unroll
    for (int bb = 0; bb < 4; ++bb) {
      const int j = lane + 64 * bb;
      const int jc = (j < PP) ? j : (PP - 1);
      float s = 0.f;
#pragma unroll
      for (int d = 0; d < 64; ++d) s += qv[d] * bf2f(Kt[d][jc]);
      sreg[bb] = (j < PP) ? s * 0.125f : -INFINITY;
    }
    // softmax (in registers, wave-wide)
    float mx = fmaxf(fmaxf(sreg[0], sreg[1]), fmaxf(sreg[2], sreg[3]));
#pragma unroll
    for (int off = 32; off; off >>= 1) mx = fmaxf(mx, __shfl_xor(mx, off));
    float p4[4], sum = 0.f;
#pragma unroll
    for (int bb = 0; bb < 4; ++bb) { p4[bb] = expf(sreg[bb] - mx); sum += p4[bb]; }
#pragma unroll
    for (int off = 32; off; off >>= 1) sum += __shfl_xor(sum, off);
    const float inv = 1.f / sum;
#pragma unroll
    for (int bb = 0; bb < 4; ++bb) p4[bb] *= inv;
    // PV: lane = d
    float o = 0.f;
#pragma unroll
    for (int jj = 0; jj < 64; ++jj) o += __shfl(p4[0], jj) * bf2f(Vt[jj][lane]);
#pragma unroll
    for (int jj = 0; jj < 64; ++jj) o += __shfl(p4[1], jj) * bf2f(Vt[64 + jj][lane]);
#pragma unroll
    for (int jj = 0; jj < 64; ++jj) o += __shfl(p4[2], jj) * bf2f(Vt[128 + jj][lane]);
#pragma unroll
    for (int jj = 0; jj < 8; ++jj) o += __shfl(p4[3], jj) * bf2f(Vt[192 + jj][lane]);
    sa[((size_t)(b_ * PP + p)) * DD + h * HDD + lane] = o;
  }
}

// K4: sa2 = sa @ out_proj_W^T + b
__global__ __launch_bounds__(256) void k_oproj(const float* __restrict__ A,
                                               const float* __restrict__ W,
                                               const float* __restrict__ bias,
                                               float* __restrict__ out)
{
  GEMM_PROLOGUE
  const int m0 = blockIdx.y * 64, n0 = blockIdx.x * 64;
  for (int k0 = 0; k0 < DD; k0 += 16) {
#pragma unroll
    for (int i = 0; i < 4; ++i) {
      const int l = tid + i * 256;
      const int kl = l & 15, ml = l >> 4;
      As[kl][ml] = A[(size_t)(m0 + ml) * DD + k0 + kl];
      Bs[kl][ml] = W[(size_t)(n0 + ml) * DD + k0 + kl];
    }
    GEMM_STEP
  }
#pragma unroll
  for (int i = 0; i < 4; ++i) {
    const int m = m0 + ty * 4 + i;
#pragma unroll
    for (int j = 0; j < 4; ++j) {
      const int n = n0 + tx * 4 + j;
      out[(size_t)m * DD + n] = acc[i][j] + bias[n];
    }
  }
}

// K5: scores[b,p,t] = (sa2[b,p,:] . tok[b,t,:]) * 0.0625
__global__ __launch_bounds__(256) void k_scores(const float* __restrict__ sa2,
                                                const float* __restrict__ down,
                                                float* __restrict__ scores)
{
  GEMM_PROLOGUE
  const int b = blockIdx.z;
  const int p0 = blockIdx.y * 64, t0 = blockIdx.x * 64;
  for (int k0 = 0; k0 < DD; k0 += 16) {
#pragma unroll
    for (int i = 0; i < 4; ++i) {
      const int l = tid + i * 256;
      const int kl = l & 15, ml = l >> 4;
      const int p = p0 + ml;
      As[kl][ml] = (p < PP) ? sa2[((size_t)b * PP + p) * DD + k0 + kl] : 0.f;
      Bs[kl][ml] = down[((size_t)b * NN + PP + t0 + ml) * DD + k0 + kl];
    }
    GEMM_STEP
  }
#pragma unroll
  for (int i = 0; i < 4; ++i) {
    const int p = p0 + ty * 4 + i;
    if (p < PP) {
#pragma unroll
      for (int j = 0; j < 4; ++j) {
        const int t = t0 + tx * 4 + j;
        scores[((size_t)b * PP + p) * TT + t] = acc[i][j] * 0.0625f;
      }
    }
  }
}

// K5b: row softmax over 1024
__global__ __launch_bounds__(256) void k_softmax(float* __restrict__ s)
{
  const int row = blockIdx.x;
  float* r = s + (size_t)row * TT;
  const int t = threadIdx.x;
  const int lane = t & 63, w = t >> 6;
  __shared__ float red[4];
  float v[4];
  float mx = -1e30f;
#pragma unroll
  for (int i = 0; i < 4; ++i) { v[i] = r[t + i * 256]; mx = fmaxf(mx, v[i]); }
#pragma unroll
  for (int off = 32; off; off >>= 1) mx = fmaxf(mx, __shfl_xor(mx, off));
  if (lane == 0) red[w] = mx;
  __syncthreads();
  mx = fmaxf(fmaxf(red[0], red[1]), fmaxf(red[2], red[3]));
  __syncthreads();
  float sum = 0.f;
#pragma unroll
  for (int i = 0; i < 4; ++i) { v[i] = expf(v[i] - mx); sum += v[i]; }
#pragma unroll
  for (int off = 32; off; off >>= 1) sum += __shfl_xor(sum, off);
  if (lane == 0) red[w] = sum;
  __syncthreads();
  sum = red[0] + red[1] + red[2] + red[3];
  const float inv = 1.f / sum;
#pragma unroll
  for (int i = 0; i < 4; ++i) r[t + i * 256] = v[i] * inv;
}

// K6: pout[b,p,e] = sum_t scores[b,p,t] * tok[b,t,e]
__global__ __launch_bounds__(256) void k_pout(const float* __restrict__ scores,
                                              const float* __restrict__ down,
                                              float* __restrict__ out)
{
  GEMM_PROLOGUE
  const int b = blockIdx.z;
  const int p0 = blockIdx.y * 64, n0 = blockIdx.x * 64;
  for (int k0 = 0; k0 < TT; k0 += 16) {
#pragma unroll
    for (int i = 0; i < 4; ++i) {
      const int l = tid + i * 256;
      {
        const int kl = l & 15, ml = l >> 4;
        const int p = p0 + ml;
        As[kl][ml] = (p < PP) ? scores[((size_t)b * PP + p) * TT + k0 + kl] : 0.f;
      }
      {
        const int nl = l & 63, kl2 = l >> 6;
        Bs[kl2][nl] = down[((size_t)b * NN + PP + k0 + kl2) * DD + n0 + nl];
      }
    }
    GEMM_STEP
  }
#pragma unroll
  for (int i = 0; i < 4; ++i) {
    const int p = p0 + ty * 4 + i;
    if (p < PP) {
#pragma unroll
      for (int j = 0; j < 4; ++j) {
        out[((size_t)b * PP + p) * DD + n0 + tx * 4 + j] = acc[i][j];
      }
    }
  }
}

extern "C" void kernel_launch(void* const* d_in, const int* in_sizes, int n_in,
                              void* d_out, int out_size, void* d_ws, size_t ws_size,
                              hipStream_t stream) {
  const float* x          = (const float*)d_in[0];
  const float* down_W     = (const float*)d_in[1];
  const float* down_b     = (const float*)d_in[2];
  const float* up_W       = (const float*)d_in[3];
  const float* up_b       = (const float*)d_in[4];
  const float* in_proj_W  = (const float*)d_in[5];
  const float* in_proj_b  = (const float*)d_in[6];
  const float* out_proj_W = (const float*)d_in[7];
  const float* out_proj_b = (const float*)d_in[8];
  const float* gate       = (const float*)d_in[9];
  float* out = (float*)d_out;

  float* ws     = (float*)d_ws;
  float* down   = ws + OFF_DOWN;
  float* qb     = ws + OFF_Q;
  float* kb     = ws + OFF_K;
  float* vb     = ws + OFF_V;
  float* sa     = ws + OFF_SA;
  float* sa2    = ws + OFF_SA2;
  float* pout   = ws + OFF_POUT;
  float* scores = ws + OFF_SCORES;

  k_down_mfma<<<dim3((BB * NN) / 128), 512, 0, stream>>>(x, down_W, down_b, down);
  k_qkv<<<dim3((3 * DD) / 64, (BB * PP) / 64), 256, 0, stream>>>(down, in_proj_W, in_proj_b, qb, kb, vb);
  k_attn2<<<dim3(BB * HH * 2), 256, 0, stream>>>(qb, kb, vb, sa);
  k_oproj<<<dim3(DD / 64, (BB * PP) / 64), 256, 0, stream>>>(sa, out_proj_W, out_proj_b, sa2);
  k_scores<<<dim3(TT / 64, 4, BB), 256, 0, stream>>>(sa2, down, scores);
  k_softmax<<<BB * PP, 256, 0, stream>>>(scores);
  k_pout<<<dim3(DD / 64, 4, BB), 256, 0, stream>>>(scores, down, pout);
  k_up_mfma<<<dim3((BB * NN) / 128, CC / 256), 512, 0, stream>>>(pout, down, up_W, up_b, gate, out);
}

// Round 3
// 654.625 us; speedup vs baseline: 3.6631x; 2.0621x over previous
//
#include <hip/hip_runtime.h>
#include <math.h>

#define BB 64
#define NN 1224
#define CC 1024
#define DD 256
#define PP 200
#define TT 1024
#define HH 4
#define HDD 64

typedef __attribute__((ext_vector_type(8))) short bf16x8;
typedef __attribute__((ext_vector_type(4))) float f32x4;

__device__ __forceinline__ unsigned short f2bf(float f) {
  union { float f; unsigned int u; } v; v.f = f;
  unsigned int r = v.u + 0x7FFF + ((v.u >> 16) & 1);
  return (unsigned short)(r >> 16);
}
__device__ __forceinline__ unsigned int pk2(float a, float b) {
  return (unsigned int)f2bf(a) | ((unsigned int)f2bf(b) << 16);
}

// ---------------- workspace layout (bytes) ----------------
static const size_t SZ_DOWN = (size_t)BB * NN * DD * 2;        // 40,108,032  bf16 [b][n][256]
static const size_t SZ_TOKT = (size_t)BB * DD * TT * 2;        // 33,554,432  bf16 [b][e][1024]
static const size_t SZ_Q    = (size_t)BB * HH * PP * HDD * 2;  //  6,553,600
static const size_t SZ_PART = (size_t)BB * PP * DD * 4;        // 13,107,200  fp32 partial

static const size_t B_DOWN   = 0;
static const size_t B_TOKT   = B_DOWN + SZ_DOWN;
static const size_t B_POOL   = B_TOKT + SZ_TOKT;
static const size_t B_QB     = B_POOL;
static const size_t B_KB     = B_QB + SZ_Q;
static const size_t B_VB     = B_KB + SZ_Q;
static const size_t B_SA     = B_VB + SZ_Q;
static const size_t B_SA2    = B_SA + SZ_Q;
static const size_t B_PBF    = B_POOL;            // alias q/k/v/sa (dead after oproj): 26,214,400
static const size_t B_POUTBF = B_SA2;             // alias sa2 (dead after scores)
static const size_t B_SCORES = B_SA2 + SZ_Q;      // fp32 52,428,800
static const size_t B_PART0  = B_SCORES;          // alias scores (dead after softmax): 4 x 13,107,200

// ================= K1: down = gelu(x @ down_W^T + b) -> bf16 =================
// M=78336, N=256, K=1024. Tile 128x256, BK=64, 8 waves.
__global__ __launch_bounds__(512) void k_down(const float* __restrict__ x,
                                              const float* __restrict__ W,
                                              const float* __restrict__ bias,
                                              unsigned short* __restrict__ out)
{
  __shared__ unsigned short Abuf[128 * 64];
  __shared__ unsigned short Bbuf[256 * 64];
  const int tid = threadIdx.x;
  const int lane = tid & 63, wave = tid >> 6;
  const int wm = wave >> 2, wn = wave & 3;
  const int m0 = blockIdx.x * 128;
  f32x4 acc[4][4] = {};
  const int rstage = tid >> 4;
  const int kc = (tid & 15) * 4;

  for (int k0 = 0; k0 < CC; k0 += 64) {
    __syncthreads();
#pragma unroll
    for (int i = 0; i < 4; ++i) {
      const int r = rstage + 32 * i;
      const float4 v = *(const float4*)&x[(size_t)(m0 + r) * CC + k0 + kc];
      uint2 p; p.x = pk2(v.x, v.y); p.y = pk2(v.z, v.w);
      const int byte = (r * 128 + kc * 2) ^ ((r & 7) << 4);
      *(uint2*)((char*)Abuf + byte) = p;
    }
#pragma unroll
    for (int i = 0; i < 8; ++i) {
      const int r = rstage + 32 * i;
      const float4 v = *(const float4*)&W[(size_t)r * CC + k0 + kc];
      uint2 p; p.x = pk2(v.x, v.y); p.y = pk2(v.z, v.w);
      const int byte = (r * 128 + kc * 2) ^ ((r & 7) << 4);
      *(uint2*)((char*)Bbuf + byte) = p;
    }
    __syncthreads();
#pragma unroll
    for (int kk = 0; kk < 64; kk += 32) {
      bf16x8 af[4], bfr[4];
#pragma unroll
      for (int mi = 0; mi < 4; ++mi) {
        const int R = wm * 64 + mi * 16 + (lane & 15);
        const int byte = (R * 128 + (kk + (lane >> 4) * 8) * 2) ^ ((R & 7) << 4);
        af[mi] = *(const bf16x8*)((const char*)Abuf + byte);
      }
#pragma unroll
      for (int ni = 0; ni < 4; ++ni) {
        const int R = wn * 64 + ni * 16 + (lane & 15);
        const int byte = (R * 128 + (kk + (lane >> 4) * 8) * 2) ^ ((R & 7) << 4);
        bfr[ni] = *(const bf16x8*)((const char*)Bbuf + byte);
      }
#pragma unroll
      for (int mi = 0; mi < 4; ++mi)
#pragma unroll
        for (int ni = 0; ni < 4; ++ni)
          acc[mi][ni] = __builtin_amdgcn_mfma_f32_16x16x32_bf16(af[mi], bfr[ni], acc[mi][ni], 0, 0, 0);
    }
  }
#pragma unroll
  for (int mi = 0; mi < 4; ++mi) {
#pragma unroll
    for (int ni = 0; ni < 4; ++ni) {
      const int col = wn * 64 + ni * 16 + (lane & 15);
      const float bv = bias[col];
#pragma unroll
      for (int r = 0; r < 4; ++r) {
        const int row = m0 + wm * 64 + mi * 16 + (lane >> 4) * 4 + r;
        float v = acc[mi][ni][r] + bv;
        v = 0.5f * v * (1.f + erff(v * 0.7071067811865475f));
        out[(size_t)row * DD + col] = f2bf(v);
      }
    }
  }
}

// ================= K1b: tokT[b][e][t] = down[b][200+t][e] =================
__global__ __launch_bounds__(256) void k_tokT(const unsigned short* __restrict__ down,
                                              unsigned short* __restrict__ tokT)
{
  __shared__ unsigned short Ls[64][68];
  const int b = blockIdx.z;
  const int t0 = blockIdx.x * 64, e0 = blockIdx.y * 64;
  const int tid = threadIdx.x;
#pragma unroll
  for (int it = 0; it < 4; ++it) {
    const int idx = tid + 256 * it;
    const int r = idx >> 4, c4 = (idx & 15) * 4;
    const unsigned long long v =
        *(const unsigned long long*)&down[((size_t)(b * NN + PP + t0 + r)) * DD + e0 + c4];
    *(unsigned long long*)&Ls[r][c4] = v;
  }
  __syncthreads();
#pragma unroll
  for (int it = 0; it < 4; ++it) {
    const int idx = tid + 256 * it;
    const int re = idx >> 4, c4 = (idx & 15) * 4;
    unsigned short v0 = Ls[c4 + 0][re];
    unsigned short v1 = Ls[c4 + 1][re];
    unsigned short v2 = Ls[c4 + 2][re];
    unsigned short v3 = Ls[c4 + 3][re];
    unsigned long long pk = (unsigned long long)v0 | ((unsigned long long)v1 << 16) |
                            ((unsigned long long)v2 << 32) | ((unsigned long long)v3 << 48);
    *(unsigned long long*)&tokT[((size_t)(b * DD + e0 + re)) * TT + t0 + c4] = pk;
  }
}

// ================= K2: qkv = prompt @ in_proj_W^T + b -> bf16 q/k/v =================
// M=12800, N-tile=256 (y: 0=q,1=k,2=v), K=256. Tile 128x256, 8 waves.
__global__ __launch_bounds__(512) void k_qkv(const unsigned short* __restrict__ down,
                                             const float* __restrict__ W,
                                             const float* __restrict__ bias,
                                             unsigned short* __restrict__ qb,
                                             unsigned short* __restrict__ kb,
                                             unsigned short* __restrict__ vb)
{
  __shared__ unsigned short Abuf[128 * 64];
  __shared__ unsigned short Bbuf[256 * 64];
  const int tid = threadIdx.x;
  const int lane = tid & 63, wave = tid >> 6;
  const int wm = wave >> 2, wn = wave & 3;
  const int m0 = blockIdx.x * 128;
  const int nt = blockIdx.y;
  f32x4 acc[4][4] = {};

  for (int k0 = 0; k0 < DD; k0 += 64) {
    __syncthreads();
#pragma unroll
    for (int it = 0; it < 4; ++it) {
      const int idx = tid + 512 * it;
      const int r = idx >> 4, c4 = (idx & 15) * 4;
      const int m = m0 + r;
      const int b = m / PP, p = m - b * PP;
      const unsigned long long v =
          *(const unsigned long long*)&down[((size_t)(b * NN + p)) * DD + k0 + c4];
      const int byte = (r * 128 + c4 * 2) ^ ((r & 7) << 4);
      *(unsigned long long*)((char*)Abuf + byte) = v;
    }
#pragma unroll
    for (int it = 0; it < 8; ++it) {
      const int idx = tid + 512 * it;
      const int r = idx >> 4, c4 = (idx & 15) * 4;
      const float4 v = *(const float4*)&W[(size_t)(nt * 256 + r) * DD + k0 + c4];
      uint2 p; p.x = pk2(v.x, v.y); p.y = pk2(v.z, v.w);
      const int byte = (r * 128 + c4 * 2) ^ ((r & 7) << 4);
      *(uint2*)((char*)Bbuf + byte) = p;
    }
    __syncthreads();
#pragma unroll
    for (int kk = 0; kk < 64; kk += 32) {
      bf16x8 af[4], bfr[4];
#pragma unroll
      for (int mi = 0; mi < 4; ++mi) {
        const int R = wm * 64 + mi * 16 + (lane & 15);
        const int byte = (R * 128 + (kk + (lane >> 4) * 8) * 2) ^ ((R & 7) << 4);
        af[mi] = *(const bf16x8*)((const char*)Abuf + byte);
      }
#pragma unroll
      for (int ni = 0; ni < 4; ++ni) {
        const int R = wn * 64 + ni * 16 + (lane & 15);
        const int byte = (R * 128 + (kk + (lane >> 4) * 8) * 2) ^ ((R & 7) << 4);
        bfr[ni] = *(const bf16x8*)((const char*)Bbuf + byte);
      }
#pragma unroll
      for (int mi = 0; mi < 4; ++mi)
#pragma unroll
        for (int ni = 0; ni < 4; ++ni)
          acc[mi][ni] = __builtin_amdgcn_mfma_f32_16x16x32_bf16(af[mi], bfr[ni], acc[mi][ni], 0, 0, 0);
    }
  }
  unsigned short* dst = (nt == 0) ? qb : ((nt == 1) ? kb : vb);
#pragma unroll
  for (int mi = 0; mi < 4; ++mi) {
#pragma unroll
    for (int ni = 0; ni < 4; ++ni) {
      const int n = wn * 64 + ni * 16 + (lane & 15);
      const float bv = bias[nt * 256 + n];
      const int h = n >> 6, dd = n & 63;
#pragma unroll
      for (int r = 0; r < 4; ++r) {
        const int m = m0 + wm * 64 + mi * 16 + (lane >> 4) * 4 + r;
        const int b = m / PP, p = m - b * PP;
        dst[(((size_t)(b * HH + h)) * PP + p) * HDD + dd] = f2bf(acc[mi][ni][r] + bv);
      }
    }
  }
}

// ================= K3: self-attention MFMA, one block per (b,h) =================
__global__ __launch_bounds__(256) void k_attn(const unsigned short* __restrict__ qb,
                                              const unsigned short* __restrict__ kb,
                                              const unsigned short* __restrict__ vb,
                                              unsigned short* __restrict__ sa)
{
  __shared__ unsigned short Ks[208 * 64];   // [j][d], XOR-swizzled, pitch 128B
  __shared__ unsigned short Vt[64 * 232];   // [d][j], pitch 232 (464B, 16B-mult)
  __shared__ unsigned short Pb[4 * 16 * 232];
  const int tid = threadIdx.x, lane = tid & 63, wave = tid >> 6;
  const int bh = blockIdx.x;
  const size_t kvbase = (size_t)bh * (PP * HDD);

  // stage K (swizzled row-major) and V (transposed)
  for (int it = 0; it < 13; ++it) {
    const int idx = tid + 256 * it;
    if (idx < 3200) {
      const int e = idx * 4;
      const int j = e >> 6, d = e & 63;
      const unsigned long long kv = *(const unsigned long long*)&kb[kvbase + e];
      const int byte = (j * 128 + d * 2) ^ ((j & 7) << 4);
      *(unsigned long long*)((char*)Ks + byte) = kv;
      const unsigned long long vv = *(const unsigned long long*)&vb[kvbase + e];
      const unsigned short* vp = (const unsigned short*)&vv;
#pragma unroll
      for (int w = 0; w < 4; ++w) Vt[(d + w) * 232 + j] = vp[w];
    }
  }
  // zero Ks rows 200-207
  if (tid < 128) {
    const int rr = 200 + (tid >> 4), c = (tid & 15) * 4;
    const int byte = (rr * 128 + c * 2) ^ ((rr & 7) << 4);
    *(unsigned long long*)((char*)Ks + byte) = 0ULL;
  }
  // zero Vt cols 200-231
#pragma unroll
  for (int w = 0; w < 2; ++w) {
    const int idx = tid + 256 * w;   // 512 u64 = 64 rows x 8 groups
    const int d = idx >> 3, cg = idx & 7;
    *(unsigned long long*)&Vt[d * 232 + 200 + cg * 4] = 0ULL;
  }
  // zero P cols 208-231 (per wave rows 0-15)
  {
    unsigned short* pw = Pb + wave * (16 * 232);
#pragma unroll
    for (int w = 0; w < 2; ++w) {
      const int idx = lane + 64 * w;
      if (idx < 96) {
        const int row = idx / 6, cg = idx - row * 6;
        *(unsigned long long*)&pw[row * 232 + 208 + cg * 4] = 0ULL;
      }
    }
  }
  __syncthreads();

  const int b_ = bh >> 2, h = bh & 3;
  const unsigned short* qbase = qb + kvbase;
  unsigned short* pw = Pb + wave * (16 * 232);

  for (int f = wave; f < 13; f += 4) {
    int qrow = f * 16 + (lane & 15); if (qrow > 199) qrow = 199;
    bf16x8 qa[2];
#pragma unroll
    for (int kk = 0; kk < 2; ++kk)
      qa[kk] = *(const bf16x8*)&qbase[(size_t)qrow * 64 + kk * 32 + (lane >> 4) * 8];

    f32x4 s[13];
#pragma unroll
    for (int nf = 0; nf < 13; ++nf) {
      const int R = nf * 16 + (lane & 15);
      f32x4 a = {};
#pragma unroll
      for (int kk = 0; kk < 2; ++kk) {
        const int byte = (R * 128 + (kk * 32 + (lane >> 4) * 8) * 2) ^ ((R & 7) << 4);
        const bf16x8 kf = *(const bf16x8*)((const char*)Ks + byte);
        a = __builtin_amdgcn_mfma_f32_16x16x32_bf16(qa[kk], kf, a, 0, 0, 0);
      }
      s[nf] = a;
    }
    // scale + mask + softmax (rows = (lane>>4)*4 + r, col group = lane&15)
    float mx[4] = {-1e30f, -1e30f, -1e30f, -1e30f};
#pragma unroll
    for (int nf = 0; nf < 13; ++nf) {
      const int col = nf * 16 + (lane & 15);
#pragma unroll
      for (int r = 0; r < 4; ++r) {
        float v = (col < PP) ? s[nf][r] * 0.125f : -INFINITY;
        s[nf][r] = v;
        mx[r] = fmaxf(mx[r], v);
      }
    }
#pragma unroll
    for (int off = 1; off < 16; off <<= 1)
#pragma unroll
      for (int r = 0; r < 4; ++r) mx[r] = fmaxf(mx[r], __shfl_xor(mx[r], off));
    float sum[4] = {0.f, 0.f, 0.f, 0.f};
#pragma unroll
    for (int nf = 0; nf < 13; ++nf)
#pragma unroll
      for (int r = 0; r < 4; ++r) {
        const float e = expf(s[nf][r] - mx[r]);
        s[nf][r] = e;
        sum[r] += e;
      }
#pragma unroll
    for (int off = 1; off < 16; off <<= 1)
#pragma unroll
      for (int r = 0; r < 4; ++r) sum[r] += __shfl_xor(sum[r], off);
    float inv[4];
#pragma unroll
    for (int r = 0; r < 4; ++r) inv[r] = 1.f / sum[r];
    // write P (bf16) to per-wave LDS
#pragma unroll
    for (int nf = 0; nf < 13; ++nf) {
      const int col = nf * 16 + (lane & 15);
#pragma unroll
      for (int r = 0; r < 4; ++r) {
        const int row = (lane >> 4) * 4 + r;
        pw[row * 232 + col] = f2bf(s[nf][r] * inv[r]);
      }
    }
    // PV
    f32x4 o[4] = {};
#pragma unroll
    for (int kk = 0; kk < 7; ++kk) {
      const bf16x8 pa = *(const bf16x8*)((const char*)pw +
                         ((lane & 15) * 232 + kk * 32 + (lane >> 4) * 8) * 2);
#pragma unroll
      for (int nf4 = 0; nf4 < 4; ++nf4) {
        const bf16x8 vv = *(const bf16x8*)((const char*)Vt +
                           (((lane & 15) + 16 * nf4) * 232 + kk * 32 + (lane >> 4) * 8) * 2);
        o[nf4] = __builtin_amdgcn_mfma_f32_16x16x32_bf16(pa, vv, o[nf4], 0, 0, 0);
      }
    }
#pragma unroll
    for (int nf4 = 0; nf4 < 4; ++nf4) {
      const int d = (lane & 15) + 16 * nf4;
#pragma unroll
      for (int r = 0; r < 4; ++r) {
        const int p = f * 16 + (lane >> 4) * 4 + r;
        if (p < PP)
          sa[((size_t)(b_ * PP + p)) * DD + h * HDD + d] = f2bf(o[nf4][r]);
      }
    }
  }
}

// ================= K4: sa2 = sa @ out_proj_W^T + b -> bf16 =================
__global__ __launch_bounds__(512) void k_oproj(const unsigned short* __restrict__ A,
                                               const float* __restrict__ W,
                                               const float* __restrict__ bias,
                                               unsigned short* __restrict__ out)
{
  __shared__ unsigned short Abuf[128 * 64];
  __shared__ unsigned short Bbuf[256 * 64];
  const int tid = threadIdx.x;
  const int lane = tid & 63, wave = tid >> 6;
  const int wm = wave >> 2, wn = wave & 3;
  const int m0 = blockIdx.x * 128;
  f32x4 acc[4][4] = {};

  for (int k0 = 0; k0 < DD; k0 += 64) {
    __syncthreads();
#pragma unroll
    for (int it = 0; it < 4; ++it) {
      const int idx = tid + 512 * it;
      const int r = idx >> 4, c4 = (idx & 15) * 4;
      const unsigned long long v =
          *(const unsigned long long*)&A[(size_t)(m0 + r) * DD + k0 + c4];
      const int byte = (r * 128 + c4 * 2) ^ ((r & 7) << 4);
      *(unsigned long long*)((char*)Abuf + byte) = v;
    }
#pragma unroll
    for (int it = 0; it < 8; ++it) {
      const int idx = tid + 512 * it;
      const int r = idx >> 4, c4 = (idx & 15) * 4;
      const float4 v = *(const float4*)&W[(size_t)r * DD + k0 + c4];
      uint2 p; p.x = pk2(v.x, v.y); p.y = pk2(v.z, v.w);
      const int byte = (r * 128 + c4 * 2) ^ ((r & 7) << 4);
      *(uint2*)((char*)Bbuf + byte) = p;
    }
    __syncthreads();
#pragma unroll
    for (int kk = 0; kk < 64; kk += 32) {
      bf16x8 af[4], bfr[4];
#pragma unroll
      for (int mi = 0; mi < 4; ++mi) {
        const int R = wm * 64 + mi * 16 + (lane & 15);
        const int byte = (R * 128 + (kk + (lane >> 4) * 8) * 2) ^ ((R & 7) << 4);
        af[mi] = *(const bf16x8*)((const char*)Abuf + byte);
      }
#pragma unroll
      for (int ni = 0; ni < 4; ++ni) {
        const int R = wn * 64 + ni * 16 + (lane & 15);
        const int byte = (R * 128 + (kk + (lane >> 4) * 8) * 2) ^ ((R & 7) << 4);
        bfr[ni] = *(const bf16x8*)((const char*)Bbuf + byte);
      }
#pragma unroll
      for (int mi = 0; mi < 4; ++mi)
#pragma unroll
        for (int ni = 0; ni < 4; ++ni)
          acc[mi][ni] = __builtin_amdgcn_mfma_f32_16x16x32_bf16(af[mi], bfr[ni], acc[mi][ni], 0, 0, 0);
    }
  }
#pragma unroll
  for (int mi = 0; mi < 4; ++mi) {
#pragma unroll
    for (int ni = 0; ni < 4; ++ni) {
      const int col = wn * 64 + ni * 16 + (lane & 15);
      const float bv = bias[col];
#pragma unroll
      for (int r = 0; r < 4; ++r) {
        const int row = m0 + wm * 64 + mi * 16 + (lane >> 4) * 4 + r;
        out[(size_t)row * DD + col] = f2bf(acc[mi][ni][r] + bv);
      }
    }
  }
}

// ================= K5: scores = (sa2 @ tok^T) * 0.0625 (fp32 out) =================
// per b: M=224(pad), N-tile=256 (4 tiles), K=256. 8 waves (2Mx4N), wm covers 112 rows.
__global__ __launch_bounds__(512) void k_scores(const unsigned short* __restrict__ sa2,
                                                const unsigned short* __restrict__ down,
                                                float* __restrict__ scores)
{
  __shared__ unsigned short Abuf[224 * 64];
  __shared__ unsigned short Bbuf[256 * 64];
  const int tid = threadIdx.x;
  const int lane = tid & 63, wave = tid >> 6;
  const int wm = wave >> 2, wn = wave & 3;
  const int b = blockIdx.x;
  const int nt = blockIdx.y;
  f32x4 acc[7][4] = {};

  for (int k0 = 0; k0 < DD; k0 += 64) {
    __syncthreads();
#pragma unroll
    for (int it = 0; it < 7; ++it) {
      const int idx = tid + 512 * it;
      const int r = idx >> 4, c4 = (idx & 15) * 4;
      const int p = (r < PP) ? r : (PP - 1);
      const unsigned long long v =
          *(const unsigned long long*)&sa2[((size_t)(b * PP + p)) * DD + k0 + c4];
      const int byte = (r * 128 + c4 * 2) ^ ((r & 7) << 4);
      *(unsigned long long*)((char*)Abuf + byte) = v;
    }
#pragma unroll
    for (int it = 0; it < 8; ++it) {
      const int idx = tid + 512 * it;
      const int r = idx >> 4, c4 = (idx & 15) * 4;
      const unsigned long long v = *(const unsigned long long*)
          &down[((size_t)(b * NN + PP + nt * 256 + r)) * DD + k0 + c4];
      const int byte = (r * 128 + c4 * 2) ^ ((r & 7) << 4);
      *(unsigned long long*)((char*)Bbuf + byte) = v;
    }
    __syncthreads();
#pragma unroll
    for (int kk = 0; kk < 64; kk += 32) {
      bf16x8 bfr[4];
#pragma unroll
      for (int ni = 0; ni < 4; ++ni) {
        const int R = wn * 64 + ni * 16 + (lane & 15);
        const int byte = (R * 128 + (kk + (lane >> 4) * 8) * 2) ^ ((R & 7) << 4);
        bfr[ni] = *(const bf16x8*)((const char*)Bbuf + byte);
      }
#pragma unroll
      for (int mf = 0; mf < 7; ++mf) {
        const int R = wm * 112 + mf * 16 + (lane & 15);
        const int byte = (R * 128 + (kk + (lane >> 4) * 8) * 2) ^ ((R & 7) << 4);
        const bf16x8 a = *(const bf16x8*)((const char*)Abuf + byte);
#pragma unroll
        for (int ni = 0; ni < 4; ++ni)
          acc[mf][ni] = __builtin_amdgcn_mfma_f32_16x16x32_bf16(a, bfr[ni], acc[mf][ni], 0, 0, 0);
      }
    }
  }
#pragma unroll
  for (int mf = 0; mf < 7; ++mf) {
#pragma unroll
    for (int ni = 0; ni < 4; ++ni) {
      const int t = nt * 256 + wn * 64 + ni * 16 + (lane & 15);
#pragma unroll
      for (int r = 0; r < 4; ++r) {
        const int p = wm * 112 + mf * 16 + (lane >> 4) * 4 + r;
        if (p < PP)
          scores[((size_t)(b * PP + p)) * TT + t] = acc[mf][ni][r] * 0.0625f;
      }
    }
  }
}

// ================= K5b: row softmax over 1024, fp32 in -> bf16 out =================
__global__ __launch_bounds__(256) void k_softmax(const float* __restrict__ s,
                                                 unsigned short* __restrict__ pbf)
{
  const int row = blockIdx.x;
  const float* r = s + (size_t)row * TT;
  const int t = threadIdx.x;
  const int lane = t & 63, w = t >> 6;
  __shared__ float red[4];
  float v[4];
  float mx = -1e30f;
#pragma unroll
  for (int i = 0; i < 4; ++i) { v[i] = r[t + i * 256]; mx = fmaxf(mx, v[i]); }
#pragma unroll
  for (int off = 32; off; off >>= 1) mx = fmaxf(mx, __shfl_xor(mx, off));
  if (lane == 0) red[w] = mx;
  __syncthreads();
  mx = fmaxf(fmaxf(red[0], red[1]), fmaxf(red[2], red[3]));
  __syncthreads();
  float sum = 0.f;
#pragma unroll
  for (int i = 0; i < 4; ++i) { v[i] = expf(v[i] - mx); sum += v[i]; }
#pragma unroll
  for (int off = 32; off; off >>= 1) sum += __shfl_xor(sum, off);
  if (lane == 0) red[w] = sum;
  __syncthreads();
  sum = red[0] + red[1] + red[2] + red[3];
  const float inv = 1.f / sum;
  unsigned short* o = pbf + (size_t)row * TT;
#pragma unroll
  for (int i = 0; i < 4; ++i) o[t + i * 256] = f2bf(v[i] * inv);
}

// ================= K6: pout partials = P @ tok (K-split by 4) =================
// per (b, ts): M=224(pad), N=256, K=256. Out fp32 partial[ts].
__global__ __launch_bounds__(512) void k_pout(const unsigned short* __restrict__ pbf,
                                              const unsigned short* __restrict__ tokT,
                                              float* __restrict__ part)
{
  __shared__ unsigned short Abuf[224 * 64];
  __shared__ unsigned short Bbuf[256 * 64];
  const int tid = threadIdx.x;
  const int lane = tid & 63, wave = tid >> 6;
  const int wm = wave >> 2, wn = wave & 3;
  const int b = blockIdx.x;
  const int ts = blockIdx.y;
  float* pout = part + (size_t)ts * ((size_t)BB * PP * DD);
  f32x4 acc[7][4] = {};

  for (int k0 = 0; k0 < 256; k0 += 64) {
    __syncthreads();
#pragma unroll
    for (int it = 0; it < 7; ++it) {
      const int idx = tid + 512 * it;
      const int r = idx >> 4, c4 = (idx & 15) * 4;
      const int p = (r < PP) ? r : (PP - 1);
      const unsigned long long v = *(const unsigned long long*)
          &pbf[((size_t)(b * PP + p)) * TT + ts * 256 + k0 + c4];
      const int byte = (r * 128 + c4 * 2) ^ ((r & 7) << 4);
      *(unsigned long long*)((char*)Abuf + byte) = v;
    }
#pragma unroll
    for (int it = 0; it < 8; ++it) {
      const int idx = tid + 512 * it;
      const int r = idx >> 4, c4 = (idx & 15) * 4;
      const unsigned long long v = *(const unsigned long long*)
          &tokT[((size_t)(b * DD + r)) * TT + ts * 256 + k0 + c4];
      const int byte = (r * 128 + c4 * 2) ^ ((r & 7) << 4);
      *(unsigned long long*)((char*)Bbuf + byte) = v;
    }
    __syncthreads();
#pragma unroll
    for (int kk = 0; kk < 64; kk += 32) {
      bf16x8 bfr[4];
#pragma unroll
      for (int ni = 0; ni < 4; ++ni) {
        const int R = wn * 64 + ni * 16 + (lane & 15);
        const int byte = (R * 128 + (kk + (lane >> 4) * 8) * 2) ^ ((R & 7) << 4);
        bfr[ni] = *(const bf16x8*)((const char*)Bbuf + byte);
      }
#pragma unroll
      for (int mf = 0; mf < 7; ++mf) {
        const int R = wm * 112 + mf * 16 + (lane & 15);
        const int byte = (R * 128 + (kk + (lane >> 4) * 8) * 2) ^ ((R & 7) << 4);
        const bf16x8 a = *(const bf16x8*)((const char*)Abuf + byte);
#pragma unroll
        for (int ni = 0; ni < 4; ++ni)
          acc[mf][ni] = __builtin_amdgcn_mfma_f32_16x16x32_bf16(a, bfr[ni], acc[mf][ni], 0, 0, 0);
      }
    }
  }
#pragma unroll
  for (int mf = 0; mf < 7; ++mf) {
#pragma unroll
    for (int ni = 0; ni < 4; ++ni) {
      const int e = wn * 64 + ni * 16 + (lane & 15);
#pragma unroll
      for (int r = 0; r < 4; ++r) {
        const int p = wm * 112 + mf * 16 + (lane >> 4) * 4 + r;
        if (p < PP)
          pout[((size_t)(b * PP + p)) * DD + e] = acc[mf][ni][r];
      }
    }
  }
}

// ================= K6b: pout_bf = sum of 4 partials -> bf16 =================
__global__ __launch_bounds__(256) void k_psum(const float* __restrict__ part,
                                              unsigned short* __restrict__ out)
{
  const size_t stride = (size_t)BB * PP * DD;
  const size_t id = (size_t)blockIdx.x * 256 + threadIdx.x;   // float4 index
  const float4 a = ((const float4*)part)[id];
  const float4 b = ((const float4*)(part + stride))[id];
  const float4 c = ((const float4*)(part + 2 * stride))[id];
  const float4 d = ((const float4*)(part + 3 * stride))[id];
  uint2 p;
  p.x = pk2(a.x + b.x + c.x + d.x, a.y + b.y + c.y + d.y);
  p.y = pk2(a.z + b.z + c.z + d.z, a.w + b.w + c.w + d.w);
  *(uint2*)&out[id * 4] = p;
}

// ================= K7: out = gate * (combined @ up_W^T + b) =================
__global__ __launch_bounds__(512) void k_up(const unsigned short* __restrict__ poutbf,
                                            const unsigned short* __restrict__ down,
                                            const float* __restrict__ W,
                                            const float* __restrict__ bias,
                                            const float* __restrict__ gate,
                                            float* __restrict__ out)
{
  __shared__ unsigned short Abuf[128 * 64];
  __shared__ unsigned short Bbuf[256 * 64];
  const int tid = threadIdx.x;
  const int lane = tid & 63, wave = tid >> 6;
  const int wm = wave >> 2, wn = wave & 3;
  const int m0 = blockIdx.x * 128;
  const int n0 = blockIdx.y * 256;
  f32x4 acc[4][4] = {};

  for (int k0 = 0; k0 < DD; k0 += 64) {
    __syncthreads();
#pragma unroll
    for (int it = 0; it < 4; ++it) {
      const int idx = tid + 512 * it;
      const int r = idx >> 4, c4 = (idx & 15) * 4;
      const int m = m0 + r;
      const int b = m / NN, rr = m - b * NN;
      const unsigned short* src = (rr < PP)
          ? &poutbf[((size_t)(b * PP + rr)) * DD]
          : &down[((size_t)(b * NN + rr)) * DD];
      const unsigned long long v = *(const unsigned long long*)&src[k0 + c4];
      const int byte = (r * 128 + c4 * 2) ^ ((r & 7) << 4);
      *(unsigned long long*)((char*)Abuf + byte) = v;
    }
#pragma unroll
    for (int it = 0; it < 8; ++it) {
      const int idx = tid + 512 * it;
      const int r = idx >> 4, c4 = (idx & 15) * 4;
      const float4 v = *(const float4*)&W[(size_t)(n0 + r) * DD + k0 + c4];
      uint2 p; p.x = pk2(v.x, v.y); p.y = pk2(v.z, v.w);
      const int byte = (r * 128 + c4 * 2) ^ ((r & 7) << 4);
      *(uint2*)((char*)Bbuf + byte) = p;
    }
    __syncthreads();
#pragma unroll
    for (int kk = 0; kk < 64; kk += 32) {
      bf16x8 af[4], bfr[4];
#pragma unroll
      for (int mi = 0; mi < 4; ++mi) {
        const int R = wm * 64 + mi * 16 + (lane & 15);
        const int byte = (R * 128 + (kk + (lane >> 4) * 8) * 2) ^ ((R & 7) << 4);
        af[mi] = *(const bf16x8*)((const char*)Abuf + byte);
      }
#pragma unroll
      for (int ni = 0; ni < 4; ++ni) {
        const int R = wn * 64 + ni * 16 + (lane & 15);
        const int byte = (R * 128 + (kk + (lane >> 4) * 8) * 2) ^ ((R & 7) << 4);
        bfr[ni] = *(const bf16x8*)((const char*)Bbuf + byte);
      }
#pragma unroll
      for (int mi = 0; mi < 4; ++mi)
#pragma unroll
        for (int ni = 0; ni < 4; ++ni)
          acc[mi][ni] = __builtin_amdgcn_mfma_f32_16x16x32_bf16(af[mi], bfr[ni], acc[mi][ni], 0, 0, 0);
    }
  }
  const float g = gate[0];
#pragma unroll
  for (int mi = 0; mi < 4; ++mi) {
#pragma unroll
    for (int ni = 0; ni < 4; ++ni) {
      const int col = n0 + wn * 64 + ni * 16 + (lane & 15);
      const float bv = bias[col];
#pragma unroll
      for (int r = 0; r < 4; ++r) {
        const int row = m0 + wm * 64 + mi * 16 + (lane >> 4) * 4 + r;
        out[(size_t)row * CC + col] = (acc[mi][ni][r] + bv) * g;
      }
    }
  }
}

extern "C" void kernel_launch(void* const* d_in, const int* in_sizes, int n_in,
                              void* d_out, int out_size, void* d_ws, size_t ws_size,
                              hipStream_t stream) {
  const float* x          = (const float*)d_in[0];
  const float* down_W     = (const float*)d_in[1];
  const float* down_b     = (const float*)d_in[2];
  const float* up_W       = (const float*)d_in[3];
  const float* up_b       = (const float*)d_in[4];
  const float* in_proj_W  = (const float*)d_in[5];
  const float* in_proj_b  = (const float*)d_in[6];
  const float* out_proj_W = (const float*)d_in[7];
  const float* out_proj_b = (const float*)d_in[8];
  const float* gate       = (const float*)d_in[9];
  float* out = (float*)d_out;

  char* wsb = (char*)d_ws;
  unsigned short* down_bf = (unsigned short*)(wsb + B_DOWN);
  unsigned short* tokT    = (unsigned short*)(wsb + B_TOKT);
  unsigned short* qb      = (unsigned short*)(wsb + B_QB);
  unsigned short* kb      = (unsigned short*)(wsb + B_KB);
  unsigned short* vb      = (unsigned short*)(wsb + B_VB);
  unsigned short* sa_bf   = (unsigned short*)(wsb + B_SA);
  unsigned short* sa2_bf  = (unsigned short*)(wsb + B_SA2);
  unsigned short* pbf     = (unsigned short*)(wsb + B_PBF);
  unsigned short* poutbf  = (unsigned short*)(wsb + B_POUTBF);
  float* scores           = (float*)(wsb + B_SCORES);
  float* part             = (float*)(wsb + B_PART0);

  k_down<<<dim3((BB * NN) / 128), 512, 0, stream>>>(x, down_W, down_b, down_bf);
  k_tokT<<<dim3(16, 4, BB), 256, 0, stream>>>(down_bf, tokT);
  k_qkv<<<dim3(100, 3), 512, 0, stream>>>(down_bf, in_proj_W, in_proj_b, qb, kb, vb);
  k_attn<<<dim3(BB * HH), 256, 0, stream>>>(qb, kb, vb, sa_bf);
  k_oproj<<<dim3(100), 512, 0, stream>>>(sa_bf, out_proj_W, out_proj_b, sa2_bf);
  k_scores<<<dim3(BB, 4), 512, 0, stream>>>(sa2_bf, down_bf, scores);
  k_softmax<<<dim3(BB * PP), 256, 0, stream>>>(scores, pbf);
  k_pout<<<dim3(BB, 4), 512, 0, stream>>>(pbf, tokT, part);
  k_psum<<<dim3(3200), 256, 0, stream>>>(part, poutbf);
  k_up<<<dim3((BB * NN) / 128, CC / 256), 512, 0, stream>>>(poutbf, down_bf, up_W, up_b, gate, out);
}

// Round 5
// 396.200 us; speedup vs baseline: 6.0523x; 1.6523x over previous
//
#include <hip/hip_runtime.h>
#include <math.h>

#define BB 64
#define NN 1224
#define CC 1024
#define DD 256
#define PP 200
#define TT 1024
#define HH 4
#define HDD 64

typedef __attribute__((ext_vector_type(8))) short bf16x8;
typedef __attribute__((ext_vector_type(4))) float f32x4;
typedef unsigned short u16;
typedef unsigned long long u64;

__device__ __forceinline__ u16 f2bf(float f) {
  union { float f; unsigned int u; } v; v.f = f;
  unsigned int r = v.u + 0x7FFF + ((v.u >> 16) & 1);
  return (u16)(r >> 16);
}
__device__ __forceinline__ unsigned int pk2(float a, float b) {
  return (unsigned int)f2bf(a) | ((unsigned int)f2bf(b) << 16);
}
__device__ __forceinline__ void gload16(const void* g, void* l) {
  __builtin_amdgcn_global_load_lds(
      (const __attribute__((address_space(1))) void*)g,
      (__attribute__((address_space(3))) void*)l, 16, 0, 0);
}

// ---------------- workspace layout (bytes) ----------------
static const size_t SZ_DOWN = (size_t)BB * NN * DD * 2;        // 40,108,032
static const size_t SZ_TOKT = (size_t)BB * DD * TT * 2;        // 33,554,432
static const size_t SZ_Q    = (size_t)BB * HH * PP * HDD * 2;  //  6,553,600
static const size_t SZ_SCORES = (size_t)BB * PP * TT * 4;      // 52,428,800

static const size_t B_DOWN   = 0;
static const size_t B_TOKT   = B_DOWN + SZ_DOWN;
static const size_t B_POOL   = B_TOKT + SZ_TOKT;
static const size_t B_QB     = B_POOL;
static const size_t B_KB     = B_QB + SZ_Q;
static const size_t B_VB     = B_KB + SZ_Q;
static const size_t B_SA     = B_VB + SZ_Q;
static const size_t B_SA2    = B_SA + SZ_Q;
static const size_t B_PBF    = B_POOL;              // alias q/k/v/sa (26,214,400 = 4*SZ_Q)
static const size_t B_POUTBF = B_SA2;               // alias sa2 (dead after k_scores)
static const size_t B_SCORES = B_SA2 + SZ_Q;
static const size_t B_W      = B_SCORES + SZ_SCORES;
static const size_t B_WD     = B_W;                 // 256x1024 bf16 = 524,288
static const size_t B_WU     = B_WD + 524288;       // 1024x256 bf16
static const size_t B_WIP    = B_WU + 524288;       // 768x256 bf16 = 393,216
static const size_t B_WOP    = B_WIP + 393216;      // 256x256 bf16 = 131,072

// ---------------- shared GEMM pieces ----------------
#define GEMM_VARS \
  const int tid = threadIdx.x; \
  const int lane = tid & 63, wave = tid >> 6; \
  const int wm = wave >> 2, wn = wave & 3; \
  f32x4 acc[4][4] = {};

#define MFMA_STEP(Ab, Bb) \
  _Pragma("unroll") \
  for (int kk = 0; kk < 64; kk += 32) { \
    bf16x8 af[4], bfr[4]; \
    _Pragma("unroll") \
    for (int mi = 0; mi < 4; ++mi) { \
      const int R = wm * 64 + mi * 16 + (lane & 15); \
      const int byt = (R * 128 + (kk + (lane >> 4) * 8) * 2) ^ ((R & 7) << 4); \
      af[mi] = *(const bf16x8*)((const char*)Ab + byt); \
    } \
    _Pragma("unroll") \
    for (int ni = 0; ni < 4; ++ni) { \
      const int R = wn * 64 + ni * 16 + (lane & 15); \
      const int byt = (R * 128 + (kk + (lane >> 4) * 8) * 2) ^ ((R & 7) << 4); \
      bfr[ni] = *(const bf16x8*)((const char*)Bb + byt); \
    } \
    _Pragma("unroll") \
    for (int mi = 0; mi < 4; ++mi) \
      _Pragma("unroll") \
      for (int ni = 0; ni < 4; ++ni) \
        acc[mi][ni] = __builtin_amdgcn_mfma_f32_16x16x32_bf16(af[mi], bfr[ni], acc[mi][ni], 0, 0, 0); \
  }

// A-tile (128x64 bf16 = 16KB): 2 issues/wave. SRC uses (r, ce).
#define GLOAD_A2(Ab, SRC) \
  _Pragma("unroll") \
  for (int ii = 0; ii < 2; ++ii) { \
    const int slot = wave * 2 + ii; \
    const int L = slot * 1024 + lane * 16; \
    const int r = L >> 7; \
    const int ce = ((L & 127) ^ ((r & 7) << 4)) >> 1; \
    gload16((SRC), (char*)Ab + slot * 1024); \
  }

// B-tile (256x64 bf16 = 32KB): 4 issues/wave.
#define GLOAD_B4(Bb, SRC) \
  _Pragma("unroll") \
  for (int ii = 0; ii < 4; ++ii) { \
    const int slot = wave * 4 + ii; \
    const int L = slot * 1024 + lane * 16; \
    const int r = L >> 7; \
    const int ce = ((L & 127) ^ ((r & 7) << 4)) >> 1; \
    gload16((SRC), (char*)Bb + slot * 1024); \
  }

// ================= K0: cast all weights to bf16 =================
__global__ __launch_bounds__(256) void k_castw(const float* __restrict__ dW,
                                               const float* __restrict__ uW,
                                               const float* __restrict__ iW,
                                               const float* __restrict__ oW,
                                               u16* __restrict__ dWb, u16* __restrict__ uWb,
                                               u16* __restrict__ iWb, u16* __restrict__ oWb)
{
  const int id = blockIdx.x * 256 + threadIdx.x;  // float4 units, 196608 total
  const float* s; u16* d; int off;
  if (id < 65536)       { s = dW; d = dWb; off = id; }
  else if (id < 131072) { s = uW; d = uWb; off = id - 65536; }
  else if (id < 180224) { s = iW; d = iWb; off = id - 131072; }
  else                  { s = oW; d = oWb; off = id - 180224; }
  const float4 v = ((const float4*)s)[off];
  uint2 p; p.x = pk2(v.x, v.y); p.y = pk2(v.z, v.w);
  *(uint2*)&d[(size_t)off * 4] = p;
}

// ================= K1: down = gelu(x @ down_W^T + b) -> bf16 =================
// A (x fp32): reg-prefetch pipeline; B (Wd bf16): global_load_lds.
__global__ __launch_bounds__(512) void k_down(const float* __restrict__ x,
                                              const u16* __restrict__ Wd,
                                              const float* __restrict__ bias,
                                              u16* __restrict__ out)
{
  __shared__ u16 Ab[128 * 64];
  __shared__ u16 Bb[256 * 64];
  GEMM_VARS
  const int m0 = blockIdx.x * 128;
  const int rstage = tid >> 4;          // 0..31
  const int kc = (tid & 15) * 4;        // 0..60

  float4 areg[4];
#pragma unroll
  for (int i = 0; i < 4; ++i)
    areg[i] = *(const float4*)&x[(size_t)(m0 + rstage + 32 * i) * CC + kc];

  for (int k0 = 0; k0 < CC; k0 += 64) {
    GLOAD_B4(Bb, &Wd[(size_t)r * CC + k0 + ce])
#pragma unroll
    for (int i = 0; i < 4; ++i) {
      const int r = rstage + 32 * i;
      uint2 p; p.x = pk2(areg[i].x, areg[i].y); p.y = pk2(areg[i].z, areg[i].w);
      const int byt = (r * 128 + kc * 2) ^ ((r & 7) << 4);
      *(uint2*)((char*)Ab + byt) = p;
    }
    __syncthreads();
    if (k0 + 64 < CC) {
#pragma unroll
      for (int i = 0; i < 4; ++i)
        areg[i] = *(const float4*)&x[(size_t)(m0 + rstage + 32 * i) * CC + k0 + 64 + kc];
    }
    MFMA_STEP(Ab, Bb)
    __syncthreads();
  }
#pragma unroll
  for (int mi = 0; mi < 4; ++mi) {
#pragma unroll
    for (int ni = 0; ni < 4; ++ni) {
      const int col = wn * 64 + ni * 16 + (lane & 15);
      const float bv = bias[col];
#pragma unroll
      for (int r = 0; r < 4; ++r) {
        const int row = m0 + wm * 64 + mi * 16 + (lane >> 4) * 4 + r;
        float v = acc[mi][ni][r] + bv;
        v = 0.5f * v * (1.f + erff(v * 0.7071067811865475f));
        out[(size_t)row * DD + col] = f2bf(v);
      }
    }
  }
}

// ================= K1b: tokT[b][e][t] = down[b][200+t][e] =================
__global__ __launch_bounds__(256) void k_tokT(const u16* __restrict__ down,
                                              u16* __restrict__ tokT)
{
  __shared__ u16 Ls[64][68];
  const int b = blockIdx.z;
  const int t0 = blockIdx.x * 64, e0 = blockIdx.y * 64;
  const int tid = threadIdx.x;
#pragma unroll
  for (int it = 0; it < 4; ++it) {
    const int idx = tid + 256 * it;
    const int r = idx >> 4, c4 = (idx & 15) * 4;
    const u64 v = *(const u64*)&down[((size_t)(b * NN + PP + t0 + r)) * DD + e0 + c4];
    *(u64*)&Ls[r][c4] = v;
  }
  __syncthreads();
#pragma unroll
  for (int it = 0; it < 4; ++it) {
    const int idx = tid + 256 * it;
    const int re = idx >> 4, c4 = (idx & 15) * 4;
    u64 pk = (u64)Ls[c4 + 0][re] | ((u64)Ls[c4 + 1][re] << 16) |
             ((u64)Ls[c4 + 2][re] << 32) | ((u64)Ls[c4 + 3][re] << 48);
    *(u64*)&tokT[((size_t)(b * DD + e0 + re)) * TT + t0 + c4] = pk;
  }
}

// ================= K2: qkv = prompt @ in_proj_W^T + b -> bf16 q/k/v =================
__global__ __launch_bounds__(512) void k_qkv(const u16* __restrict__ down,
                                             const u16* __restrict__ Wip,
                                             const float* __restrict__ bias,
                                             u16* __restrict__ qb,
                                             u16* __restrict__ kb,
                                             u16* __restrict__ vb)
{
  __shared__ u16 Ab[128 * 64];
  __shared__ u16 Bb[256 * 64];
  GEMM_VARS
  const int m0 = blockIdx.x * 128;
  const int nt = blockIdx.y;

  for (int k0 = 0; k0 < DD; k0 += 64) {
    GLOAD_A2(Ab, ({ const int m = m0 + r; const int b = m / PP; const int p = m - b * PP;
                    &down[((size_t)(b * NN + p)) * DD + k0 + ce]; }))
    GLOAD_B4(Bb, &Wip[(size_t)(nt * 256 + r) * DD + k0 + ce])
    __syncthreads();
    MFMA_STEP(Ab, Bb)
    __syncthreads();
  }
  u16* dst = (nt == 0) ? qb : ((nt == 1) ? kb : vb);
#pragma unroll
  for (int mi = 0; mi < 4; ++mi) {
#pragma unroll
    for (int ni = 0; ni < 4; ++ni) {
      const int n = wn * 64 + ni * 16 + (lane & 15);
      const float bv = bias[nt * 256 + n];
      const int h = n >> 6, dd = n & 63;
#pragma unroll
      for (int r = 0; r < 4; ++r) {
        const int m = m0 + wm * 64 + mi * 16 + (lane >> 4) * 4 + r;
        const int b = m / PP, p = m - b * PP;
        dst[(((size_t)(b * HH + h)) * PP + p) * HDD + dd] = f2bf(acc[mi][ni][r] + bv);
      }
    }
  }
}

// ================= K3: self-attention MFMA, one block per (b,h) =================
__global__ __launch_bounds__(256) void k_attn(const u16* __restrict__ qb,
                                              const u16* __restrict__ kb,
                                              const u16* __restrict__ vb,
                                              u16* __restrict__ sa)
{
  __shared__ u16 Ks[208 * 64];
  __shared__ u16 Vt[64 * 232];
  __shared__ u16 Pb[4 * 16 * 232];
  const int tid = threadIdx.x, lane = tid & 63, wave = tid >> 6;
  const int bh = blockIdx.x;
  const size_t kvbase = (size_t)bh * (PP * HDD);

  for (int it = 0; it < 13; ++it) {
    const int idx = tid + 256 * it;
    if (idx < 3200) {
      const int e = idx * 4;
      const int j = e >> 6, d = e & 63;
      const u64 kv = *(const u64*)&kb[kvbase + e];
      const int byt = (j * 128 + d * 2) ^ ((j & 7) << 4);
      *(u64*)((char*)Ks + byt) = kv;
      const u64 vv = *(const u64*)&vb[kvbase + e];
      const u16* vp = (const u16*)&vv;
#pragma unroll
      for (int w = 0; w < 4; ++w) Vt[(d + w) * 232 + j] = vp[w];
    }
  }
  if (tid < 128) {
    const int rr = 200 + (tid >> 4), c = (tid & 15) * 4;
    const int byt = (rr * 128 + c * 2) ^ ((rr & 7) << 4);
    *(u64*)((char*)Ks + byt) = 0ULL;
  }
#pragma unroll
  for (int w = 0; w < 2; ++w) {
    const int idx = tid + 256 * w;
    const int d = idx >> 3, cg = idx & 7;
    *(u64*)&Vt[d * 232 + 200 + cg * 4] = 0ULL;
  }
  {
    u16* pw = Pb + wave * (16 * 232);
#pragma unroll
    for (int w = 0; w < 2; ++w) {
      const int idx = lane + 64 * w;
      if (idx < 96) {
        const int row = idx / 6, cg = idx - row * 6;
        *(u64*)&pw[row * 232 + 208 + cg * 4] = 0ULL;
      }
    }
  }
  __syncthreads();

  const int b_ = bh >> 2, h = bh & 3;
  const u16* qbase = qb + kvbase;
  u16* pw = Pb + wave * (16 * 232);

  for (int f = wave; f < 13; f += 4) {
    int qrow = f * 16 + (lane & 15); if (qrow > 199) qrow = 199;
    bf16x8 qa[2];
#pragma unroll
    for (int kk = 0; kk < 2; ++kk)
      qa[kk] = *(const bf16x8*)&qbase[(size_t)qrow * 64 + kk * 32 + (lane >> 4) * 8];

    f32x4 s[13];
#pragma unroll
    for (int nf = 0; nf < 13; ++nf) {
      const int R = nf * 16 + (lane & 15);
      f32x4 a = {};
#pragma unroll
      for (int kk = 0; kk < 2; ++kk) {
        const int byt = (R * 128 + (kk * 32 + (lane >> 4) * 8) * 2) ^ ((R & 7) << 4);
        const bf16x8 kf = *(const bf16x8*)((const char*)Ks + byt);
        a = __builtin_amdgcn_mfma_f32_16x16x32_bf16(qa[kk], kf, a, 0, 0, 0);
      }
      s[nf] = a;
    }
    float mx[4] = {-1e30f, -1e30f, -1e30f, -1e30f};
#pragma unroll
    for (int nf = 0; nf < 13; ++nf) {
      const int col = nf * 16 + (lane & 15);
#pragma unroll
      for (int r = 0; r < 4; ++r) {
        float v = (col < PP) ? s[nf][r] * 0.125f : -INFINITY;
        s[nf][r] = v;
        mx[r] = fmaxf(mx[r], v);
      }
    }
#pragma unroll
    for (int off = 1; off < 16; off <<= 1)
#pragma unroll
      for (int r = 0; r < 4; ++r) mx[r] = fmaxf(mx[r], __shfl_xor(mx[r], off));
    float sum[4] = {0.f, 0.f, 0.f, 0.f};
#pragma unroll
    for (int nf = 0; nf < 13; ++nf)
#pragma unroll
      for (int r = 0; r < 4; ++r) {
        const float e = expf(s[nf][r] - mx[r]);
        s[nf][r] = e;
        sum[r] += e;
      }
#pragma unroll
    for (int off = 1; off < 16; off <<= 1)
#pragma unroll
      for (int r = 0; r < 4; ++r) sum[r] += __shfl_xor(sum[r], off);
    float inv[4];
#pragma unroll
    for (int r = 0; r < 4; ++r) inv[r] = 1.f / sum[r];
#pragma unroll
    for (int nf = 0; nf < 13; ++nf) {
      const int col = nf * 16 + (lane & 15);
#pragma unroll
      for (int r = 0; r < 4; ++r) {
        const int row = (lane >> 4) * 4 + r;
        pw[row * 232 + col] = f2bf(s[nf][r] * inv[r]);
      }
    }
    f32x4 o[4] = {};
#pragma unroll
    for (int kk = 0; kk < 7; ++kk) {
      const bf16x8 pa = *(const bf16x8*)((const char*)pw +
                         ((lane & 15) * 232 + kk * 32 + (lane >> 4) * 8) * 2);
#pragma unroll
      for (int nf4 = 0; nf4 < 4; ++nf4) {
        const bf16x8 vv = *(const bf16x8*)((const char*)Vt +
                           (((lane & 15) + 16 * nf4) * 232 + kk * 32 + (lane >> 4) * 8) * 2);
        o[nf4] = __builtin_amdgcn_mfma_f32_16x16x32_bf16(pa, vv, o[nf4], 0, 0, 0);
      }
    }
#pragma unroll
    for (int nf4 = 0; nf4 < 4; ++nf4) {
      const int d = (lane & 15) + 16 * nf4;
#pragma unroll
      for (int r = 0; r < 4; ++r) {
        const int p = f * 16 + (lane >> 4) * 4 + r;
        if (p < PP)
          sa[((size_t)(b_ * PP + p)) * DD + h * HDD + d] = f2bf(o[nf4][r]);
      }
    }
  }
}

// ================= K4: sa2 = sa @ out_proj_W^T + b -> bf16 =================
__global__ __launch_bounds__(512) void k_oproj(const u16* __restrict__ A,
                                               const u16* __restrict__ Wop,
                                               const float* __restrict__ bias,
                                               u16* __restrict__ out)
{
  __shared__ u16 Ab[128 * 64];
  __shared__ u16 Bb[256 * 64];
  GEMM_VARS
  const int m0 = blockIdx.x * 128;

  for (int k0 = 0; k0 < DD; k0 += 64) {
    GLOAD_A2(Ab, &A[(size_t)(m0 + r) * DD + k0 + ce])
    GLOAD_B4(Bb, &Wop[(size_t)r * DD + k0 + ce])
    __syncthreads();
    MFMA_STEP(Ab, Bb)
    __syncthreads();
  }
#pragma unroll
  for (int mi = 0; mi < 4; ++mi) {
#pragma unroll
    for (int ni = 0; ni < 4; ++ni) {
      const int col = wn * 64 + ni * 16 + (lane & 15);
      const float bv = bias[col];
#pragma unroll
      for (int r = 0; r < 4; ++r) {
        const int row = m0 + wm * 64 + mi * 16 + (lane >> 4) * 4 + r;
        out[(size_t)row * DD + col] = f2bf(acc[mi][ni][r] + bv);
      }
    }
  }
}

// ================= K5: scores = (sa2 @ tok^T) * 0.0625 (fp32 out) =================
// grid (b, mh, nt): M=128 (clamped), N=256.
__global__ __launch_bounds__(512) void k_scores(const u16* __restrict__ sa2,
                                                const u16* __restrict__ down,
                                                float* __restrict__ scores)
{
  __shared__ u16 Ab[128 * 64];
  __shared__ u16 Bb[256 * 64];
  GEMM_VARS
  const int b = blockIdx.x, mh = blockIdx.y, nt = blockIdx.z;

  for (int k0 = 0; k0 < DD; k0 += 64) {
    GLOAD_A2(Ab, ({ int p = mh * 128 + r; p = (p < PP) ? p : (PP - 1);
                    &sa2[((size_t)(b * PP + p)) * DD + k0 + ce]; }))
    GLOAD_B4(Bb, &down[((size_t)(b * NN + PP + nt * 256 + r)) * DD + k0 + ce])
    __syncthreads();
    MFMA_STEP(Ab, Bb)
    __syncthreads();
  }
#pragma unroll
  for (int mi = 0; mi < 4; ++mi) {
#pragma unroll
    for (int ni = 0; ni < 4; ++ni) {
      const int t = nt * 256 + wn * 64 + ni * 16 + (lane & 15);
#pragma unroll
      for (int r = 0; r < 4; ++r) {
        const int p = mh * 128 + wm * 64 + mi * 16 + (lane >> 4) * 4 + r;
        if (p < PP)
          scores[((size_t)(b * PP + p)) * TT + t] = acc[mi][ni][r] * 0.0625f;
      }
    }
  }
}

// ================= K5b: row softmax over 1024, fp32 in -> bf16 out =================
__global__ __launch_bounds__(256) void k_softmax(const float* __restrict__ s,
                                                 u16* __restrict__ pbf)
{
  const int row = blockIdx.x;
  const float* r = s + (size_t)row * TT;
  const int t = threadIdx.x;
  const int lane = t & 63, w = t >> 6;
  __shared__ float red[4];
  float v[4];
  float mx = -1e30f;
#pragma unroll
  for (int i = 0; i < 4; ++i) { v[i] = r[t + i * 256]; mx = fmaxf(mx, v[i]); }
#pragma unroll
  for (int off = 32; off; off >>= 1) mx = fmaxf(mx, __shfl_xor(mx, off));
  if (lane == 0) red[w] = mx;
  __syncthreads();
  mx = fmaxf(fmaxf(red[0], red[1]), fmaxf(red[2], red[3]));
  __syncthreads();
  float sum = 0.f;
#pragma unroll
  for (int i = 0; i < 4; ++i) { v[i] = expf(v[i] - mx); sum += v[i]; }
#pragma unroll
  for (int off = 32; off; off >>= 1) sum += __shfl_xor(sum, off);
  if (lane == 0) red[w] = sum;
  __syncthreads();
  sum = red[0] + red[1] + red[2] + red[3];
  const float inv = 1.f / sum;
  u16* o = pbf + (size_t)row * TT;
#pragma unroll
  for (int i = 0; i < 4; ++i) o[t + i * 256] = f2bf(v[i] * inv);
}

// ================= K6: pout = P @ tok -> bf16, single pass =================
// grid (b, mh): M=128 (clamped), N=256, K=1024.
__global__ __launch_bounds__(512) void k_pout(const u16* __restrict__ pbf,
                                              const u16* __restrict__ tokT,
                                              u16* __restrict__ out)
{
  __shared__ u16 Ab[128 * 64];
  __shared__ u16 Bb[256 * 64];
  GEMM_VARS
  const int b = blockIdx.x, mh = blockIdx.y;

  for (int k0 = 0; k0 < TT; k0 += 64) {
    GLOAD_A2(Ab, ({ int p = mh * 128 + r; p = (p < PP) ? p : (PP - 1);
                    &pbf[((size_t)(b * PP + p)) * TT + k0 + ce]; }))
    GLOAD_B4(Bb, &tokT[((size_t)(b * DD + r)) * TT + k0 + ce])
    __syncthreads();
    MFMA_STEP(Ab, Bb)
    __syncthreads();
  }
#pragma unroll
  for (int mi = 0; mi < 4; ++mi) {
#pragma unroll
    for (int ni = 0; ni < 4; ++ni) {
      const int e = wn * 64 + ni * 16 + (lane & 15);
#pragma unroll
      for (int r = 0; r < 4; ++r) {
        const int p = mh * 128 + wm * 64 + mi * 16 + (lane >> 4) * 4 + r;
        if (p < PP)
          out[((size_t)(b * PP + p)) * DD + e] = f2bf(acc[mi][ni][r]);
      }
    }
  }
}

// ================= K7: out = gate * (combined @ up_W^T + b) =================
__global__ __launch_bounds__(512) void k_up(const u16* __restrict__ poutbf,
                                            const u16* __restrict__ down,
                                            const u16* __restrict__ Wu,
                                            const float* __restrict__ bias,
                                            const float* __restrict__ gate,
                                            float* __restrict__ out)
{
  __shared__ u16 Ab[128 * 64];
  __shared__ u16 Bb[256 * 64];
  GEMM_VARS
  const int m0 = blockIdx.x * 128;
  const int n0 = blockIdx.y * 256;

  for (int k0 = 0; k0 < DD; k0 += 64) {
    GLOAD_A2(Ab, ({ const int m = m0 + r; const int b = m / NN; const int rr = m - b * NN;
                    const u16* base = (rr < PP) ? &poutbf[((size_t)(b * PP + rr)) * DD]
                                                : &down[((size_t)(b * NN + rr)) * DD];
                    base + k0 + ce; }))
    GLOAD_B4(Bb, &Wu[(size_t)(n0 + r) * DD + k0 + ce])
    __syncthreads();
    MFMA_STEP(Ab, Bb)
    __syncthreads();
  }
  const float g = gate[0];
#pragma unroll
  for (int mi = 0; mi < 4; ++mi) {
#pragma unroll
    for (int ni = 0; ni < 4; ++ni) {
      const int col = n0 + wn * 64 + ni * 16 + (lane & 15);
      const float bv = bias[col];
#pragma unroll
      for (int r = 0; r < 4; ++r) {
        const int row = m0 + wm * 64 + mi * 16 + (lane >> 4) * 4 + r;
        out[(size_t)row * CC + col] = (acc[mi][ni][r] + bv) * g;
      }
    }
  }
}

extern "C" void kernel_launch(void* const* d_in, const int* in_sizes, int n_in,
                              void* d_out, int out_size, void* d_ws, size_t ws_size,
                              hipStream_t stream) {
  const float* x          = (const float*)d_in[0];
  const float* down_W     = (const float*)d_in[1];
  const float* down_b     = (const float*)d_in[2];
  const float* up_W       = (const float*)d_in[3];
  const float* up_b       = (const float*)d_in[4];
  const float* in_proj_W  = (const float*)d_in[5];
  const float* in_proj_b  = (const float*)d_in[6];
  const float* out_proj_W = (const float*)d_in[7];
  const float* out_proj_b = (const float*)d_in[8];
  const float* gate       = (const float*)d_in[9];
  float* out = (float*)d_out;

  char* wsb = (char*)d_ws;
  u16* down_bf = (u16*)(wsb + B_DOWN);
  u16* tokT    = (u16*)(wsb + B_TOKT);
  u16* qb      = (u16*)(wsb + B_QB);
  u16* kb      = (u16*)(wsb + B_KB);
  u16* vb      = (u16*)(wsb + B_VB);
  u16* sa_bf   = (u16*)(wsb + B_SA);
  u16* sa2_bf  = (u16*)(wsb + B_SA2);
  u16* pbf     = (u16*)(wsb + B_PBF);
  u16* poutbf  = (u16*)(wsb + B_POUTBF);
  float* scores = (float*)(wsb + B_SCORES);
  u16* Wd  = (u16*)(wsb + B_WD);
  u16* Wu  = (u16*)(wsb + B_WU);
  u16* Wip = (u16*)(wsb + B_WIP);
  u16* Wop = (u16*)(wsb + B_WOP);

  k_castw<<<dim3(768), 256, 0, stream>>>(down_W, up_W, in_proj_W, out_proj_W, Wd, Wu, Wip, Wop);
  k_down<<<dim3((BB * NN) / 128), 512, 0, stream>>>(x, Wd, down_b, down_bf);
  k_tokT<<<dim3(16, 4, BB), 256, 0, stream>>>(down_bf, tokT);
  k_qkv<<<dim3(100, 3), 512, 0, stream>>>(down_bf, Wip, in_proj_b, qb, kb, vb);
  k_attn<<<dim3(BB * HH), 256, 0, stream>>>(qb, kb, vb, sa_bf);
  k_oproj<<<dim3(100), 512, 0, stream>>>(sa_bf, Wop, out_proj_b, sa2_bf);
  k_scores<<<dim3(BB, 2, 4), 512, 0, stream>>>(sa2_bf, down_bf, scores);
  k_softmax<<<dim3(BB * PP), 256, 0, stream>>>(scores, pbf);
  k_pout<<<dim3(BB, 2), 512, 0, stream>>>(pbf, tokT, poutbf);
  k_up<<<dim3((BB * NN) / 128, CC / 256), 512, 0, stream>>>(poutbf, down_bf, Wu, up_b, gate, out);
}

// Round 6
// 371.858 us; speedup vs baseline: 6.4485x; 1.0655x over previous
//
#include <hip/hip_runtime.h>
#include <math.h>

#define BB 64
#define NN 1224
#define CC 1024
#define DD 256
#define PP 200
#define TT 1024
#define HH 4
#define HDD 64

typedef __attribute__((ext_vector_type(8))) short bf16x8;
typedef __attribute__((ext_vector_type(4))) float f32x4;
typedef unsigned short u16;
typedef unsigned long long u64;

__device__ __forceinline__ u16 f2bf(float f) {
  union { float f; unsigned int u; } v; v.f = f;
  unsigned int r = v.u + 0x7FFF + ((v.u >> 16) & 1);
  return (u16)(r >> 16);
}
__device__ __forceinline__ float bf2f(u16 h) {
  union { unsigned int u; float f; } v; v.u = ((unsigned int)h) << 16;
  return v.f;
}
__device__ __forceinline__ unsigned int pk2(float a, float b) {
  return (unsigned int)f2bf(a) | ((unsigned int)f2bf(b) << 16);
}
__device__ __forceinline__ void gload16(const void* g, void* l) {
  __builtin_amdgcn_global_load_lds(
      (const __attribute__((address_space(1))) void*)g,
      (__attribute__((address_space(3))) void*)l, 16, 0, 0);
}

// ---------------- workspace layout (bytes) ----------------
static const size_t SZ_DOWN = (size_t)BB * NN * DD * 2;        // 40,108,032
static const size_t SZ_TOKT = (size_t)BB * DD * TT * 2;        // 33,554,432
static const size_t SZ_Q    = (size_t)BB * HH * PP * HDD * 2;  //  6,553,600
static const size_t SZ_SCORES = (size_t)BB * PP * TT * 2;      // 26,214,400 bf16 raw

static const size_t B_DOWN   = 0;
static const size_t B_TOKT   = B_DOWN + SZ_DOWN;
static const size_t B_POOL   = B_TOKT + SZ_TOKT;
static const size_t B_QB     = B_POOL;
static const size_t B_KB     = B_QB + SZ_Q;
static const size_t B_VB     = B_KB + SZ_Q;
static const size_t B_SA     = B_VB + SZ_Q;
static const size_t B_SA2    = B_SA + SZ_Q;
static const size_t B_PBF    = B_POOL;              // alias q/k/v/sa (dead after oproj)
static const size_t B_POUTBF = B_SA2;               // alias sa2 (dead after k_scores)
static const size_t B_SCORES = B_SA2 + SZ_Q;        // raw bf16 scores
static const size_t B_W      = B_SCORES + SZ_SCORES * 2;  // keep old headroom
static const size_t B_WD     = B_W;                 // 256x1024 bf16
static const size_t B_WU     = B_WD + 524288;       // 1024x256 bf16
static const size_t B_WIP    = B_WU + 524288;       // 768x256 bf16
static const size_t B_WOP    = B_WIP + 393216;      // 256x256 bf16

// ---------------- 128x256-tile GEMM pieces (mid kernels) ----------------
#define GEMM_VARS \
  const int tid = threadIdx.x; \
  const int lane = tid & 63, wave = tid >> 6; \
  const int wm = wave >> 2, wn = wave & 3; \
  f32x4 acc[4][4] = {};

#define MFMA_STEP(Ab, Bb) \
  _Pragma("unroll") \
  for (int kk = 0; kk < 64; kk += 32) { \
    bf16x8 af[4], bfr[4]; \
    _Pragma("unroll") \
    for (int mi = 0; mi < 4; ++mi) { \
      const int R = wm * 64 + mi * 16 + (lane & 15); \
      const int byt = (R * 128 + (kk + (lane >> 4) * 8) * 2) ^ ((R & 7) << 4); \
      af[mi] = *(const bf16x8*)((const char*)Ab + byt); \
    } \
    _Pragma("unroll") \
    for (int ni = 0; ni < 4; ++ni) { \
      const int R = wn * 64 + ni * 16 + (lane & 15); \
      const int byt = (R * 128 + (kk + (lane >> 4) * 8) * 2) ^ ((R & 7) << 4); \
      bfr[ni] = *(const bf16x8*)((const char*)Bb + byt); \
    } \
    _Pragma("unroll") \
    for (int mi = 0; mi < 4; ++mi) \
      _Pragma("unroll") \
      for (int ni = 0; ni < 4; ++ni) \
        acc[mi][ni] = __builtin_amdgcn_mfma_f32_16x16x32_bf16(af[mi], bfr[ni], acc[mi][ni], 0, 0, 0); \
  }

#define GLOAD_A2(Ab, SRC) \
  _Pragma("unroll") \
  for (int ii = 0; ii < 2; ++ii) { \
    const int slot = wave * 2 + ii; \
    const int L = slot * 1024 + lane * 16; \
    const int r = L >> 7; \
    const int ce = ((L & 127) ^ ((r & 7) << 4)) >> 1; \
    gload16((SRC), (char*)Ab + slot * 1024); \
  }

#define GLOAD_B4(Bb, SRC) \
  _Pragma("unroll") \
  for (int ii = 0; ii < 4; ++ii) { \
    const int slot = wave * 4 + ii; \
    const int L = slot * 1024 + lane * 16; \
    const int r = L >> 7; \
    const int ce = ((L & 127) ^ ((r & 7) << 4)) >> 1; \
    gload16((SRC), (char*)Bb + slot * 1024); \
  }

// ---------------- 64x256-tile pieces (k_down / k_up) ----------------
#define MFMA_STEP64(Ab, Bb) \
  _Pragma("unroll") \
  for (int kk = 0; kk < 64; kk += 32) { \
    bf16x8 af[4], bfr[2]; \
    _Pragma("unroll") \
    for (int mi = 0; mi < 4; ++mi) { \
      const int R = mi * 16 + (lane & 15); \
      const int byt = (R * 128 + (kk + (lane >> 4) * 8) * 2) ^ ((R & 7) << 4); \
      af[mi] = *(const bf16x8*)((const char*)Ab + byt); \
    } \
    _Pragma("unroll") \
    for (int ni = 0; ni < 2; ++ni) { \
      const int R = wave * 32 + ni * 16 + (lane & 15); \
      const int byt = (R * 128 + (kk + (lane >> 4) * 8) * 2) ^ ((R & 7) << 4); \
      bfr[ni] = *(const bf16x8*)((const char*)Bb + byt); \
    } \
    _Pragma("unroll") \
    for (int mi = 0; mi < 4; ++mi) \
      _Pragma("unroll") \
      for (int ni = 0; ni < 2; ++ni) \
        acc[mi][ni] = __builtin_amdgcn_mfma_f32_16x16x32_bf16(af[mi], bfr[ni], acc[mi][ni], 0, 0, 0); \
  }

#define GLOAD_A1(Ab, SRC) \
  { \
    const int L = wave * 1024 + lane * 16; \
    const int r = L >> 7; \
    const int ce = ((L & 127) ^ ((r & 7) << 4)) >> 1; \
    gload16((SRC), (char*)Ab + wave * 1024); \
  }

// ================= K0: cast all weights to bf16 =================
__global__ __launch_bounds__(256) void k_castw(const float* __restrict__ dW,
                                               const float* __restrict__ uW,
                                               const float* __restrict__ iW,
                                               const float* __restrict__ oW,
                                               u16* __restrict__ dWb, u16* __restrict__ uWb,
                                               u16* __restrict__ iWb, u16* __restrict__ oWb)
{
  const int id = blockIdx.x * 256 + threadIdx.x;
  const float* s; u16* d; int off;
  if (id < 65536)       { s = dW; d = dWb; off = id; }
  else if (id < 131072) { s = uW; d = uWb; off = id - 65536; }
  else if (id < 180224) { s = iW; d = iWb; off = id - 131072; }
  else                  { s = oW; d = oWb; off = id - 180224; }
  const float4 v = ((const float4*)s)[off];
  uint2 p; p.x = pk2(v.x, v.y); p.y = pk2(v.z, v.w);
  *(uint2*)&d[(size_t)off * 4] = p;
}

// ================= K1: down = gelu(x @ down_W^T + b) -> bf16 =================
// 64x256 tile, 8 waves 1Mx8N, acc[4][2]=32 VGPR. A: reg-prefetch; B: gload_lds.
__global__ __launch_bounds__(512, 6) void k_down(const float* __restrict__ x,
                                                 const u16* __restrict__ Wd,
                                                 const float* __restrict__ bias,
                                                 u16* __restrict__ out)
{
  __shared__ u16 Ab[64 * 64];
  __shared__ u16 Bb[256 * 64];
  const int tid = threadIdx.x;
  const int lane = tid & 63, wave = tid >> 6;
  f32x4 acc[4][2] = {};
  const int m0 = blockIdx.x * 64;
  const int ar0 = tid >> 4;             // 0..31
  const int c4 = (tid & 15) * 4;        // 0..60

  float4 areg[2];
#pragma unroll
  for (int i = 0; i < 2; ++i)
    areg[i] = *(const float4*)&x[(size_t)(m0 + ar0 + 32 * i) * CC + c4];

  for (int k0 = 0; k0 < CC; k0 += 64) {
    GLOAD_B4(Bb, &Wd[(size_t)r * CC + k0 + ce])
#pragma unroll
    for (int i = 0; i < 2; ++i) {
      const int r = ar0 + 32 * i;
      uint2 p; p.x = pk2(areg[i].x, areg[i].y); p.y = pk2(areg[i].z, areg[i].w);
      const int byt = (r * 128 + c4 * 2) ^ ((r & 7) << 4);
      *(uint2*)((char*)Ab + byt) = p;
    }
    __syncthreads();
    if (k0 + 64 < CC) {
#pragma unroll
      for (int i = 0; i < 2; ++i)
        areg[i] = *(const float4*)&x[(size_t)(m0 + ar0 + 32 * i) * CC + k0 + 64 + c4];
    }
    MFMA_STEP64(Ab, Bb)
    __syncthreads();
  }
#pragma unroll
  for (int mi = 0; mi < 4; ++mi) {
#pragma unroll
    for (int ni = 0; ni < 2; ++ni) {
      const int col = wave * 32 + ni * 16 + (lane & 15);
      const float bv = bias[col];
#pragma unroll
      for (int r = 0; r < 4; ++r) {
        const int row = m0 + mi * 16 + (lane >> 4) * 4 + r;
        float v = acc[mi][ni][r] + bv;
        v = 0.5f * v * (1.f + erff(v * 0.7071067811865475f));
        out[(size_t)row * DD + col] = f2bf(v);
      }
    }
  }
}

// ================= K1b: tokT[b][e][t] = down[b][200+t][e] =================
__global__ __launch_bounds__(256) void k_tokT(const u16* __restrict__ down,
                                              u16* __restrict__ tokT)
{
  __shared__ u16 Ls[64][68];
  const int b = blockIdx.z;
  const int t0 = blockIdx.x * 64, e0 = blockIdx.y * 64;
  const int tid = threadIdx.x;
#pragma unroll
  for (int it = 0; it < 4; ++it) {
    const int idx = tid + 256 * it;
    const int r = idx >> 4, c4 = (idx & 15) * 4;
    const u64 v = *(const u64*)&down[((size_t)(b * NN + PP + t0 + r)) * DD + e0 + c4];
    *(u64*)&Ls[r][c4] = v;
  }
  __syncthreads();
#pragma unroll
  for (int it = 0; it < 4; ++it) {
    const int idx = tid + 256 * it;
    const int re = idx >> 4, c4 = (idx & 15) * 4;
    u64 pk = (u64)Ls[c4 + 0][re] | ((u64)Ls[c4 + 1][re] << 16) |
             ((u64)Ls[c4 + 2][re] << 32) | ((u64)Ls[c4 + 3][re] << 48);
    *(u64*)&tokT[((size_t)(b * DD + e0 + re)) * TT + t0 + c4] = pk;
  }
}

// ================= K2: qkv = prompt @ in_proj_W^T + b -> bf16 q/k/v =================
__global__ __launch_bounds__(512) void k_qkv(const u16* __restrict__ down,
                                             const u16* __restrict__ Wip,
                                             const float* __restrict__ bias,
                                             u16* __restrict__ qb,
                                             u16* __restrict__ kb,
                                             u16* __restrict__ vb)
{
  __shared__ u16 Ab[128 * 64];
  __shared__ u16 Bb[256 * 64];
  GEMM_VARS
  const int m0 = blockIdx.x * 128;
  const int nt = blockIdx.y;

  for (int k0 = 0; k0 < DD; k0 += 64) {
    GLOAD_A2(Ab, ({ const int m = m0 + r; const int b = m / PP; const int p = m - b * PP;
                    &down[((size_t)(b * NN + p)) * DD + k0 + ce]; }))
    GLOAD_B4(Bb, &Wip[(size_t)(nt * 256 + r) * DD + k0 + ce])
    __syncthreads();
    MFMA_STEP(Ab, Bb)
    __syncthreads();
  }
  u16* dst = (nt == 0) ? qb : ((nt == 1) ? kb : vb);
#pragma unroll
  for (int mi = 0; mi < 4; ++mi) {
#pragma unroll
    for (int ni = 0; ni < 4; ++ni) {
      const int n = wn * 64 + ni * 16 + (lane & 15);
      const float bv = bias[nt * 256 + n];
      const int h = n >> 6, dd = n & 63;
#pragma unroll
      for (int r = 0; r < 4; ++r) {
        const int m = m0 + wm * 64 + mi * 16 + (lane >> 4) * 4 + r;
        const int b = m / PP, p = m - b * PP;
        dst[(((size_t)(b * HH + h)) * PP + p) * HDD + dd] = f2bf(acc[mi][ni][r] + bv);
      }
    }
  }
}

// ================= K3: self-attention MFMA, one block per (b,h) =================
__global__ __launch_bounds__(256) void k_attn(const u16* __restrict__ qb,
                                              const u16* __restrict__ kb,
                                              const u16* __restrict__ vb,
                                              u16* __restrict__ sa)
{
  __shared__ u16 Ks[208 * 64];
  __shared__ u16 Vt[64 * 232];
  __shared__ u16 Pb[4 * 16 * 232];
  const int tid = threadIdx.x, lane = tid & 63, wave = tid >> 6;
  const int bh = blockIdx.x;
  const size_t kvbase = (size_t)bh * (PP * HDD);

  for (int it = 0; it < 13; ++it) {
    const int idx = tid + 256 * it;
    if (idx < 3200) {
      const int e = idx * 4;
      const int j = e >> 6, d = e & 63;
      const u64 kv = *(const u64*)&kb[kvbase + e];
      const int byt = (j * 128 + d * 2) ^ ((j & 7) << 4);
      *(u64*)((char*)Ks + byt) = kv;
      const u64 vv = *(const u64*)&vb[kvbase + e];
      const u16* vp = (const u16*)&vv;
#pragma unroll
      for (int w = 0; w < 4; ++w) Vt[(d + w) * 232 + j] = vp[w];
    }
  }
  if (tid < 128) {
    const int rr = 200 + (tid >> 4), c = (tid & 15) * 4;
    const int byt = (rr * 128 + c * 2) ^ ((rr & 7) << 4);
    *(u64*)((char*)Ks + byt) = 0ULL;
  }
#pragma unroll
  for (int w = 0; w < 2; ++w) {
    const int idx = tid + 256 * w;
    const int d = idx >> 3, cg = idx & 7;
    *(u64*)&Vt[d * 232 + 200 + cg * 4] = 0ULL;
  }
  {
    u16* pw = Pb + wave * (16 * 232);
#pragma unroll
    for (int w = 0; w < 2; ++w) {
      const int idx = lane + 64 * w;
      if (idx < 96) {
        const int row = idx / 6, cg = idx - row * 6;
        *(u64*)&pw[row * 232 + 208 + cg * 4] = 0ULL;
      }
    }
  }
  __syncthreads();

  const int b_ = bh >> 2, h = bh & 3;
  const u16* qbase = qb + kvbase;
  u16* pw = Pb + wave * (16 * 232);

  for (int f = wave; f < 13; f += 4) {
    int qrow = f * 16 + (lane & 15); if (qrow > 199) qrow = 199;
    bf16x8 qa[2];
#pragma unroll
    for (int kk = 0; kk < 2; ++kk)
      qa[kk] = *(const bf16x8*)&qbase[(size_t)qrow * 64 + kk * 32 + (lane >> 4) * 8];

    f32x4 s[13];
#pragma unroll
    for (int nf = 0; nf < 13; ++nf) {
      const int R = nf * 16 + (lane & 15);
      f32x4 a = {};
#pragma unroll
      for (int kk = 0; kk < 2; ++kk) {
        const int byt = (R * 128 + (kk * 32 + (lane >> 4) * 8) * 2) ^ ((R & 7) << 4);
        const bf16x8 kf = *(const bf16x8*)((const char*)Ks + byt);
        a = __builtin_amdgcn_mfma_f32_16x16x32_bf16(qa[kk], kf, a, 0, 0, 0);
      }
      s[nf] = a;
    }
    float mx[4] = {-1e30f, -1e30f, -1e30f, -1e30f};
#pragma unroll
    for (int nf = 0; nf < 13; ++nf) {
      const int col = nf * 16 + (lane & 15);
#pragma unroll
      for (int r = 0; r < 4; ++r) {
        float v = (col < PP) ? s[nf][r] * 0.125f : -INFINITY;
        s[nf][r] = v;
        mx[r] = fmaxf(mx[r], v);
      }
    }
#pragma unroll
    for (int off = 1; off < 16; off <<= 1)
#pragma unroll
      for (int r = 0; r < 4; ++r) mx[r] = fmaxf(mx[r], __shfl_xor(mx[r], off));
    float sum[4] = {0.f, 0.f, 0.f, 0.f};
#pragma unroll
    for (int nf = 0; nf < 13; ++nf)
#pragma unroll
      for (int r = 0; r < 4; ++r) {
        const float e = expf(s[nf][r] - mx[r]);
        s[nf][r] = e;
        sum[r] += e;
      }
#pragma unroll
    for (int off = 1; off < 16; off <<= 1)
#pragma unroll
      for (int r = 0; r < 4; ++r) sum[r] += __shfl_xor(sum[r], off);
    float inv[4];
#pragma unroll
    for (int r = 0; r < 4; ++r) inv[r] = 1.f / sum[r];
#pragma unroll
    for (int nf = 0; nf < 13; ++nf) {
      const int col = nf * 16 + (lane & 15);
#pragma unroll
      for (int r = 0; r < 4; ++r) {
        const int row = (lane >> 4) * 4 + r;
        pw[row * 232 + col] = f2bf(s[nf][r] * inv[r]);
      }
    }
    f32x4 o[4] = {};
#pragma unroll
    for (int kk = 0; kk < 7; ++kk) {
      const bf16x8 pa = *(const bf16x8*)((const char*)pw +
                         ((lane & 15) * 232 + kk * 32 + (lane >> 4) * 8) * 2);
#pragma unroll
      for (int nf4 = 0; nf4 < 4; ++nf4) {
        const bf16x8 vv = *(const bf16x8*)((const char*)Vt +
                           (((lane & 15) + 16 * nf4) * 232 + kk * 32 + (lane >> 4) * 8) * 2);
        o[nf4] = __builtin_amdgcn_mfma_f32_16x16x32_bf16(pa, vv, o[nf4], 0, 0, 0);
      }
    }
#pragma unroll
    for (int nf4 = 0; nf4 < 4; ++nf4) {
      const int d = (lane & 15) + 16 * nf4;
#pragma unroll
      for (int r = 0; r < 4; ++r) {
        const int p = f * 16 + (lane >> 4) * 4 + r;
        if (p < PP)
          sa[((size_t)(b_ * PP + p)) * DD + h * HDD + d] = f2bf(o[nf4][r]);
      }
    }
  }
}

// ================= K4: sa2 = sa @ out_proj_W^T + b -> bf16 =================
__global__ __launch_bounds__(512) void k_oproj(const u16* __restrict__ A,
                                               const u16* __restrict__ Wop,
                                               const float* __restrict__ bias,
                                               u16* __restrict__ out)
{
  __shared__ u16 Ab[128 * 64];
  __shared__ u16 Bb[256 * 64];
  GEMM_VARS
  const int m0 = blockIdx.x * 128;

  for (int k0 = 0; k0 < DD; k0 += 64) {
    GLOAD_A2(Ab, &A[(size_t)(m0 + r) * DD + k0 + ce])
    GLOAD_B4(Bb, &Wop[(size_t)r * DD + k0 + ce])
    __syncthreads();
    MFMA_STEP(Ab, Bb)
    __syncthreads();
  }
#pragma unroll
  for (int mi = 0; mi < 4; ++mi) {
#pragma unroll
    for (int ni = 0; ni < 4; ++ni) {
      const int col = wn * 64 + ni * 16 + (lane & 15);
      const float bv = bias[col];
#pragma unroll
      for (int r = 0; r < 4; ++r) {
        const int row = m0 + wm * 64 + mi * 16 + (lane >> 4) * 4 + r;
        out[(size_t)row * DD + col] = f2bf(acc[mi][ni][r] + bv);
      }
    }
  }
}

// ================= K5: scores_raw = (sa2 @ tok^T) * 0.0625 -> bf16 =================
__global__ __launch_bounds__(512) void k_scores(const u16* __restrict__ sa2,
                                                const u16* __restrict__ down,
                                                u16* __restrict__ scores)
{
  __shared__ u16 Ab[128 * 64];
  __shared__ u16 Bb[256 * 64];
  GEMM_VARS
  const int b = blockIdx.x, mh = blockIdx.y, nt = blockIdx.z;

  for (int k0 = 0; k0 < DD; k0 += 64) {
    GLOAD_A2(Ab, ({ int p = mh * 128 + r; p = (p < PP) ? p : (PP - 1);
                    &sa2[((size_t)(b * PP + p)) * DD + k0 + ce]; }))
    GLOAD_B4(Bb, &down[((size_t)(b * NN + PP + nt * 256 + r)) * DD + k0 + ce])
    __syncthreads();
    MFMA_STEP(Ab, Bb)
    __syncthreads();
  }
#pragma unroll
  for (int mi = 0; mi < 4; ++mi) {
#pragma unroll
    for (int ni = 0; ni < 4; ++ni) {
      const int t = nt * 256 + wn * 64 + ni * 16 + (lane & 15);
#pragma unroll
      for (int r = 0; r < 4; ++r) {
        const int p = mh * 128 + wm * 64 + mi * 16 + (lane >> 4) * 4 + r;
        if (p < PP)
          scores[((size_t)(b * PP + p)) * TT + t] = f2bf(acc[mi][ni][r] * 0.0625f);
      }
    }
  }
}

// ================= K5b: row softmax over 1024, bf16 in -> bf16 out =================
__global__ __launch_bounds__(256) void k_softmax(const u16* __restrict__ s,
                                                 u16* __restrict__ pbf)
{
  const int row = blockIdx.x;
  const int t = threadIdx.x;
  const int lane = t & 63, w = t >> 6;
  __shared__ float red[4];
  const u64 raw = *(const u64*)&s[(size_t)row * TT + t * 4];
  float v[4];
#pragma unroll
  for (int i = 0; i < 4; ++i) v[i] = bf2f((u16)(raw >> (16 * i)));
  float mx = fmaxf(fmaxf(v[0], v[1]), fmaxf(v[2], v[3]));
#pragma unroll
  for (int off = 32; off; off >>= 1) mx = fmaxf(mx, __shfl_xor(mx, off));
  if (lane == 0) red[w] = mx;
  __syncthreads();
  mx = fmaxf(fmaxf(red[0], red[1]), fmaxf(red[2], red[3]));
  __syncthreads();
  float sum = 0.f;
#pragma unroll
  for (int i = 0; i < 4; ++i) { v[i] = expf(v[i] - mx); sum += v[i]; }
#pragma unroll
  for (int off = 32; off; off >>= 1) sum += __shfl_xor(sum, off);
  if (lane == 0) red[w] = sum;
  __syncthreads();
  sum = red[0] + red[1] + red[2] + red[3];
  const float inv = 1.f / sum;
  u64 pk = (u64)f2bf(v[0] * inv) | ((u64)f2bf(v[1] * inv) << 16) |
           ((u64)f2bf(v[2] * inv) << 32) | ((u64)f2bf(v[3] * inv) << 48);
  *(u64*)&pbf[(size_t)row * TT + t * 4] = pk;
}

// ================= K6: pout = P @ tok -> bf16, single pass =================
__global__ __launch_bounds__(512) void k_pout(const u16* __restrict__ pbf,
                                              const u16* __restrict__ tokT,
                                              u16* __restrict__ out)
{
  __shared__ u16 Ab[128 * 64];
  __shared__ u16 Bb[256 * 64];
  GEMM_VARS
  const int b = blockIdx.x, mh = blockIdx.y;

  for (int k0 = 0; k0 < TT; k0 += 64) {
    GLOAD_A2(Ab, ({ int p = mh * 128 + r; p = (p < PP) ? p : (PP - 1);
                    &pbf[((size_t)(b * PP + p)) * TT + k0 + ce]; }))
    GLOAD_B4(Bb, &tokT[((size_t)(b * DD + r)) * TT + k0 + ce])
    __syncthreads();
    MFMA_STEP(Ab, Bb)
    __syncthreads();
  }
#pragma unroll
  for (int mi = 0; mi < 4; ++mi) {
#pragma unroll
    for (int ni = 0; ni < 4; ++ni) {
      const int e = wn * 64 + ni * 16 + (lane & 15);
#pragma unroll
      for (int r = 0; r < 4; ++r) {
        const int p = mh * 128 + wm * 64 + mi * 16 + (lane >> 4) * 4 + r;
        if (p < PP)
          out[((size_t)(b * PP + p)) * DD + e] = f2bf(acc[mi][ni][r]);
      }
    }
  }
}

// ================= K7: out = gate * (combined @ up_W^T + b) =================
// 64x256 tile, 8 waves 1Mx8N. grid (1224, 4).
__global__ __launch_bounds__(512, 6) void k_up(const u16* __restrict__ poutbf,
                                               const u16* __restrict__ down,
                                               const u16* __restrict__ Wu,
                                               const float* __restrict__ bias,
                                               const float* __restrict__ gate,
                                               float* __restrict__ out)
{
  __shared__ u16 Ab[64 * 64];
  __shared__ u16 Bb[256 * 64];
  const int tid = threadIdx.x;
  const int lane = tid & 63, wave = tid >> 6;
  f32x4 acc[4][2] = {};
  const int m0 = blockIdx.x * 64;
  const int n0 = blockIdx.y * 256;

  for (int k0 = 0; k0 < DD; k0 += 64) {
    GLOAD_A1(Ab, ({ const int m = m0 + r; const int b = m / NN; const int rr = m - b * NN;
                    const u16* base = (rr < PP) ? &poutbf[((size_t)(b * PP + rr)) * DD]
                                                : &down[((size_t)(b * NN + rr)) * DD];
                    base + k0 + ce; }))
    GLOAD_B4(Bb, &Wu[(size_t)(n0 + r) * DD + k0 + ce])
    __syncthreads();
    MFMA_STEP64(Ab, Bb)
    __syncthreads();
  }
  const float g = gate[0];
#pragma unroll
  for (int mi = 0; mi < 4; ++mi) {
#pragma unroll
    for (int ni = 0; ni < 2; ++ni) {
      const int col = n0 + wave * 32 + ni * 16 + (lane & 15);
      const float bv = bias[col];
#pragma unroll
      for (int r = 0; r < 4; ++r) {
        const int row = m0 + mi * 16 + (lane >> 4) * 4 + r;
        out[(size_t)row * CC + col] = (acc[mi][ni][r] + bv) * g;
      }
    }
  }
}

extern "C" void kernel_launch(void* const* d_in, const int* in_sizes, int n_in,
                              void* d_out, int out_size, void* d_ws, size_t ws_size,
                              hipStream_t stream) {
  const float* x          = (const float*)d_in[0];
  const float* down_W     = (const float*)d_in[1];
  const float* down_b     = (const float*)d_in[2];
  const float* up_W       = (const float*)d_in[3];
  const float* up_b       = (const float*)d_in[4];
  const float* in_proj_W  = (const float*)d_in[5];
  const float* in_proj_b  = (const float*)d_in[6];
  const float* out_proj_W = (const float*)d_in[7];
  const float* out_proj_b = (const float*)d_in[8];
  const float* gate       = (const float*)d_in[9];
  float* out = (float*)d_out;

  char* wsb = (char*)d_ws;
  u16* down_bf = (u16*)(wsb + B_DOWN);
  u16* tokT    = (u16*)(wsb + B_TOKT);
  u16* qb      = (u16*)(wsb + B_QB);
  u16* kb      = (u16*)(wsb + B_KB);
  u16* vb      = (u16*)(wsb + B_VB);
  u16* sa_bf   = (u16*)(wsb + B_SA);
  u16* sa2_bf  = (u16*)(wsb + B_SA2);
  u16* pbf     = (u16*)(wsb + B_PBF);
  u16* poutbf  = (u16*)(wsb + B_POUTBF);
  u16* scores  = (u16*)(wsb + B_SCORES);
  u16* Wd  = (u16*)(wsb + B_WD);
  u16* Wu  = (u16*)(wsb + B_WU);
  u16* Wip = (u16*)(wsb + B_WIP);
  u16* Wop = (u16*)(wsb + B_WOP);

  k_castw<<<dim3(768), 256, 0, stream>>>(down_W, up_W, in_proj_W, out_proj_W, Wd, Wu, Wip, Wop);
  k_down<<<dim3((BB * NN) / 64), 512, 0, stream>>>(x, Wd, down_b, down_bf);
  k_tokT<<<dim3(16, 4, BB), 256, 0, stream>>>(down_bf, tokT);
  k_qkv<<<dim3(100, 3), 512, 0, stream>>>(down_bf, Wip, in_proj_b, qb, kb, vb);
  k_attn<<<dim3(BB * HH), 256, 0, stream>>>(qb, kb, vb, sa_bf);
  k_oproj<<<dim3(100), 512, 0, stream>>>(sa_bf, Wop, out_proj_b, sa2_bf);
  k_scores<<<dim3(BB, 2, 4), 512, 0, stream>>>(sa2_bf, down_bf, scores);
  k_softmax<<<dim3(BB * PP), 256, 0, stream>>>(scores, pbf);
  k_pout<<<dim3(BB, 2), 512, 0, stream>>>(pbf, tokT, poutbf);
  k_up<<<dim3((BB * NN) / 64, CC / 256), 512, 0, stream>>>(poutbf, down_bf, Wu, up_b, gate, out);
}